// Round 1
// baseline (215.810 us; speedup 1.0000x reference)
//
#include <hip/hip_runtime.h>
#include <hip/hip_bf16.h>

typedef unsigned short u16;
typedef short short8 __attribute__((ext_vector_type(8)));
typedef float f32x4 __attribute__((ext_vector_type(4)));
typedef unsigned short u16x8 __attribute__((ext_vector_type(8)));

#define BB 4
#define NS 512
#define EE 1024
#define HH 16
#define DD 64
#define MM (BB*NS)   // 2048

__device__ __forceinline__ u16 f2bf(float x) {
  union { float f; unsigned int u; } v; v.f = x;
  unsigned int r = v.u + 0x7fffu + ((v.u >> 16) & 1u);
  return (u16)(r >> 16);
}

__device__ __forceinline__ void gload_lds16(const void* g, void* l) {
  __builtin_amdgcn_global_load_lds(
      (const __attribute__((address_space(1))) unsigned int*)g,
      (__attribute__((address_space(3))) unsigned int*)l, 16, 0, 0);
}

// ---------------- converts ----------------

__global__ void cvt_inputs(const float* __restrict__ q, const float* __restrict__ k,
                           const float* __restrict__ v,
                           u16* __restrict__ qb, u16* __restrict__ kb, u16* __restrict__ vb) {
  size_t g = (size_t)blockIdx.x * 256 + threadIdx.x;
  size_t e = g << 3;                          // 8 elements / thread
  int seg = (int)(e >> 21);                   // 2048*1024 = 2^21 per tensor
  size_t off = e & ((1u << 21) - 1);
  const float* src = seg == 0 ? q : (seg == 1 ? k : v);
  u16* dst = seg == 0 ? qb : (seg == 1 ? kb : vb);
  float4 f0 = *(const float4*)(src + off);
  float4 f1 = *(const float4*)(src + off + 4);
  u16x8 r;
  r[0] = f2bf(f0.x); r[1] = f2bf(f0.y); r[2] = f2bf(f0.z); r[3] = f2bf(f0.w);
  r[4] = f2bf(f1.x); r[5] = f2bf(f1.y); r[6] = f2bf(f1.z); r[7] = f2bf(f1.w);
  *(u16x8*)(dst + off) = r;
}

__global__ void cvt_w(const float* __restrict__ Wq, const float* __restrict__ Wk,
                      const float* __restrict__ Wv, const float* __restrict__ Wo,
                      u16* __restrict__ WqT, u16* __restrict__ WkT,
                      u16* __restrict__ WvT, u16* __restrict__ WoT) {
  int z = blockIdx.z;
  const float* W = z == 0 ? Wq : z == 1 ? Wk : z == 2 ? Wv : Wo;
  u16* WT = z == 0 ? WqT : z == 1 ? WkT : z == 2 ? WvT : WoT;
  int n0 = blockIdx.x << 5, k0 = blockIdx.y << 5;
  __shared__ float tile[32][33];
  int tx = threadIdx.x & 31, ty = threadIdx.x >> 5;   // 32x8
  #pragma unroll
  for (int i = 0; i < 4; ++i) {
    int r = (i << 3) + ty;
    tile[r][tx] = W[(size_t)(k0 + r) * EE + n0 + tx];
  }
  __syncthreads();
  #pragma unroll
  for (int i = 0; i < 4; ++i) {
    int r = (i << 3) + ty;                            // n-local
    WT[(size_t)(n0 + r) * EE + k0 + tx] = f2bf(tile[tx][r]);
  }
}

__global__ void cvt_w_small(const float* __restrict__ W2, const float* __restrict__ W3,
                            u16* __restrict__ W2T, u16* __restrict__ W3T) {
  int tid = threadIdx.x;
  for (int i = tid; i < 4096; i += 256) {
    int n = i >> 6, k = i & 63;
    W2T[i] = f2bf(W2[k * 64 + n]);
  }
  for (int i = tid; i < 1024; i += 256) {
    int n = i >> 6, k = i & 63;   // n 0..15
    W3T[i] = f2bf(W3[k * 16 + n]);
  }
}

// ---------------- hi / hj ----------------

__global__ void hi_hj_kernel(const float* __restrict__ se, const float* __restrict__ W1,
                             const float* __restrict__ b1,
                             float* __restrict__ hi, float* __restrict__ hj) {
  int tid = threadIdx.x;
  int row = blockIdx.x * 4 + (tid >> 6);
  int c = tid & 63;
  float ah = b1[c], aj = 0.f;
  #pragma unroll 8
  for (int k = 0; k < 64; ++k) {
    float s = se[row * 64 + k];
    ah += s * W1[k * 64 + c];
    aj += s * W1[(k + 64) * 64 + c];
  }
  hi[row * 64 + c] = ah;   // b1 folded into hi
  hj[row * 64 + c] = aj;
}

// ---------------- main GEMM (M x 1024 @ 1024 x 1024, Bt = [N][K]) ----------------

template <bool F32OUT>
__device__ __forceinline__ void gemm_body(const u16* __restrict__ A, const u16* __restrict__ Bt,
                                          const float* __restrict__ bias, void* __restrict__ Cout) {
  __shared__ u16 As[128 * 32];
  __shared__ u16 Bs[128 * 32];
  const int tid = threadIdx.x, lane = tid & 63, wave = tid >> 6;
  const int m0 = blockIdx.x * 128, n0 = blockIdx.y * 128;
  const int wr = wave >> 1, wc = wave & 1;

  const f32x4 zero = {0.f, 0.f, 0.f, 0.f};
  f32x4 acc[4][4];
  #pragma unroll
  for (int i = 0; i < 4; ++i)
    #pragma unroll
    for (int j = 0; j < 4; ++j) acc[i][j] = zero;

  const int rA = lane >> 2;            // row within 16-row chunk
  const int cA = (lane & 3) << 3;      // k sub-offset (elements)

  for (int kt = 0; kt < EE; kt += 32) {
    #pragma unroll
    for (int i = 0; i < 2; ++i) {
      int base = ((i << 2) + wave) << 9;           // element offset of wave chunk
      int row = (base >> 5) + rA;
      gload_lds16(A  + (size_t)(m0 + row) * EE + kt + cA, As + base);
      gload_lds16(Bt + (size_t)(n0 + row) * EE + kt + cA, Bs + base);
    }
    __syncthreads();
    short8 af[4], bfr[4];
    #pragma unroll
    for (int mf = 0; mf < 4; ++mf) {
      int row = wr * 64 + mf * 16 + (lane & 15);
      af[mf] = *(const short8*)(As + row * 32 + ((lane >> 4) << 3));
    }
    #pragma unroll
    for (int nf = 0; nf < 4; ++nf) {
      int row = wc * 64 + nf * 16 + (lane & 15);
      bfr[nf] = *(const short8*)(Bs + row * 32 + ((lane >> 4) << 3));
    }
    #pragma unroll
    for (int mf = 0; mf < 4; ++mf)
      #pragma unroll
      for (int nf = 0; nf < 4; ++nf)
        acc[mf][nf] = __builtin_amdgcn_mfma_f32_16x16x32_bf16(af[mf], bfr[nf], acc[mf][nf], 0, 0, 0);
    __syncthreads();
  }

  #pragma unroll
  for (int mf = 0; mf < 4; ++mf) {
    #pragma unroll
    for (int nf = 0; nf < 4; ++nf) {
      int col = n0 + wc * 64 + nf * 16 + (lane & 15);
      float bv = bias[col];
      #pragma unroll
      for (int j = 0; j < 4; ++j) {
        int rowm = m0 + wr * 64 + mf * 16 + ((lane >> 4) << 2) + j;
        float v = acc[mf][nf][j] + bv;
        if (F32OUT) ((float*)Cout)[(size_t)rowm * EE + col] = v;
        else        ((u16*)Cout)[(size_t)rowm * EE + col] = f2bf(v);
      }
    }
  }
}

__global__ __launch_bounds__(256, 2) void gemm_proj(
    const u16* __restrict__ qb, const u16* __restrict__ kb, const u16* __restrict__ vb,
    const u16* __restrict__ WqT, const u16* __restrict__ WkT, const u16* __restrict__ WvT,
    const float* __restrict__ bq, const float* __restrict__ bk, const float* __restrict__ bv_,
    u16* __restrict__ qp, u16* __restrict__ kp, u16* __restrict__ vp) {
  int z = blockIdx.z;
  const u16* A = z == 0 ? qb : (z == 1 ? kb : vb);
  const u16* Bt = z == 0 ? WqT : (z == 1 ? WkT : WvT);
  const float* bias = z == 0 ? bq : (z == 1 ? bk : bv_);
  u16* C = z == 0 ? qp : (z == 1 ? kp : vp);
  gemm_body<false>(A, Bt, bias, C);
}

__global__ __launch_bounds__(256, 2) void gemm_final(
    const u16* __restrict__ A, const u16* __restrict__ WoT,
    const float* __restrict__ bo, float* __restrict__ C) {
  gemm_body<true>(A, WoT, bo, C);
}

// ---------------- transpose V: [B,N,H,D] -> [B,H,D,N] ----------------

__global__ void transpose_v(const u16* __restrict__ vp, u16* __restrict__ vT) {
  int id = blockIdx.x;               // b*256 + h*16 + ntile
  int b = id >> 8, rem = id & 255, h = rem >> 4, nt = rem & 15;
  int n0 = nt << 5;
  __shared__ u16 tile[32][72];
  int tid = threadIdx.x;
  int tx = tid & 63, ty = tid >> 6;
  #pragma unroll
  for (int i = 0; i < 8; ++i) {
    int r = (i << 2) + ty;
    tile[r][tx] = vp[(size_t)(b * NS + n0 + r) * EE + (h << 6) + tx];
  }
  __syncthreads();
  int nl = tid & 31, dsub = tid >> 5;   // dsub 0..7
  #pragma unroll
  for (int i = 0; i < 8; ++i) {
    int d = (i << 3) + dsub;
    vT[(size_t)((b * HH + h) * DD + d) * NS + n0 + nl] = tile[nl][d];
  }
}

// ---------------- fused CAB-bias MLP + QK^T -> scores ----------------

__global__ __launch_bounds__(256, 2) void bias_scores(
    const float* __restrict__ hi, const float* __restrict__ hj,
    const u16* __restrict__ W2T, const u16* __restrict__ W3T,
    const float* __restrict__ b2, const float* __restrict__ b3,
    const float* __restrict__ temps,
    const u16* __restrict__ qp, const u16* __restrict__ kp,
    float* __restrict__ scores) {
  const int st = blockIdx.x, tt = blockIdx.y, b = blockIdx.z;
  const int t0 = tt << 4, s0 = st << 4;
  const int tid = threadIdx.x, lane = tid & 63, wave = tid >> 6;

  __shared__ float hi_s[16][64];
  __shared__ float hj_s[16][64];
  __shared__ u16 X[256 * 64];        // pair-rows x HID, XOR-swizzled, reused for Y
  __shared__ float comp[256][16];

  for (int i = tid; i < 1024; i += 256) {
    int r = i >> 6, c = i & 63;
    hi_s[r][c] = hi[(b * NS + t0 + r) * 64 + c];
    hj_s[r][c] = hj[(b * NS + s0 + r) * 64 + c];
  }
  __syncthreads();

  // X[p][c] = relu(hi'[tl][c] + hj[sl][c]); p = tl*16 + sl; wave owns rows [wave*64, wave*64+64)
  {
    const int c = tid & 63;
    for (int i = 0; i < 64; ++i) {
      int p = ((tid >> 6) << 6) + i;
      int tl = p >> 4, sl = p & 15;
      float x = hi_s[tl][c] + hj_s[sl][c];
      x = fmaxf(x, 0.0f);
      int e = (p << 6) + c;
      e ^= ((p & 7) << 3);
      X[e] = f2bf(x);
    }
  }
  __syncthreads();

  const f32x4 zero = {0.f, 0.f, 0.f, 0.f};

  // layer 2: Y = relu(X @ W2 + b2) on this wave's 64 rows
  short8 a2[4][2], bw[4][2];
  #pragma unroll
  for (int nf = 0; nf < 4; ++nf)
    #pragma unroll
    for (int kk = 0; kk < 2; ++kk)
      bw[nf][kk] = *(const short8*)(W2T + (nf * 16 + (lane & 15)) * 64 + kk * 32 + ((lane >> 4) << 3));
  #pragma unroll
  for (int mf = 0; mf < 4; ++mf) {
    int row = (wave << 6) + mf * 16 + (lane & 15);
    #pragma unroll
    for (int kk = 0; kk < 2; ++kk) {
      int e = (row << 6) + kk * 32 + ((lane >> 4) << 3);
      e ^= ((row & 7) << 3);
      a2[mf][kk] = *(const short8*)(X + e);
    }
  }
  f32x4 accY[4][4];
  #pragma unroll
  for (int i = 0; i < 4; ++i)
    #pragma unroll
    for (int j = 0; j < 4; ++j) accY[i][j] = zero;
  #pragma unroll
  for (int mf = 0; mf < 4; ++mf)
    #pragma unroll
    for (int nf = 0; nf < 4; ++nf)
      #pragma unroll
      for (int kk = 0; kk < 2; ++kk)
        accY[mf][nf] = __builtin_amdgcn_mfma_f32_16x16x32_bf16(a2[mf][kk], bw[nf][kk], accY[mf][nf], 0, 0, 0);

  // write Y (relu, bf16) back into X, same rows/swizzle (wave-private rows)
  #pragma unroll
  for (int mf = 0; mf < 4; ++mf)
    #pragma unroll
    for (int nf = 0; nf < 4; ++nf) {
      int col = nf * 16 + (lane & 15);
      float bb = b2[col];
      #pragma unroll
      for (int j = 0; j < 4; ++j) {
        int row = (wave << 6) + mf * 16 + ((lane >> 4) << 2) + j;
        float y = fmaxf(accY[mf][nf][j] + bb, 0.f);
        int e = (row << 6) + col;
        e ^= ((row & 7) << 3);
        X[e] = f2bf(y);
      }
    }

  // layer 3: comp = Y @ W3 + b3 (16 outputs)
  short8 bw3[2];
  #pragma unroll
  for (int kk = 0; kk < 2; ++kk)
    bw3[kk] = *(const short8*)(W3T + (lane & 15) * 64 + kk * 32 + ((lane >> 4) << 3));
  f32x4 accC[4];
  #pragma unroll
  for (int i = 0; i < 4; ++i) accC[i] = zero;
  #pragma unroll
  for (int mf = 0; mf < 4; ++mf) {
    int row = (wave << 6) + mf * 16 + (lane & 15);
    #pragma unroll
    for (int kk = 0; kk < 2; ++kk) {
      int e = (row << 6) + kk * 32 + ((lane >> 4) << 3);
      e ^= ((row & 7) << 3);
      short8 a3 = *(const short8*)(X + e);
      accC[mf] = __builtin_amdgcn_mfma_f32_16x16x32_bf16(a3, bw3[kk], accC[mf], 0, 0, 0);
    }
  }
  {
    int h = lane & 15;
    float tb = b3[h], tm = temps[h];
    #pragma unroll
    for (int mf = 0; mf < 4; ++mf)
      #pragma unroll
      for (int j = 0; j < 4; ++j) {
        int p = (wave << 6) + mf * 16 + ((lane >> 4) << 2) + j;
        comp[p][h] = (accC[mf][j] + tb) * tm;
      }
  }
  __syncthreads();

  // QK^T + bias; wave handles heads 4*wave..4*wave+3
  const float scale = 0.125f;
  #pragma unroll
  for (int hh = 0; hh < 4; ++hh) {
    int h = (wave << 2) + hh;
    short8 aq[2], bk_[2];
    #pragma unroll
    for (int kk = 0; kk < 2; ++kk) {
      aq[kk]  = *(const short8*)(qp + (size_t)(b * NS + t0 + (lane & 15)) * EE + h * 64 + kk * 32 + ((lane >> 4) << 3));
      bk_[kk] = *(const short8*)(kp + (size_t)(b * NS + s0 + (lane & 15)) * EE + h * 64 + kk * 32 + ((lane >> 4) << 3));
    }
    f32x4 accS = zero;
    accS = __builtin_amdgcn_mfma_f32_16x16x32_bf16(aq[0], bk_[0], accS, 0, 0, 0);
    accS = __builtin_amdgcn_mfma_f32_16x16x32_bf16(aq[1], bk_[1], accS, 0, 0, 0);
    #pragma unroll
    for (int j = 0; j < 4; ++j) {
      int tl = ((lane >> 4) << 2) + j, sl = lane & 15;
      float v = accS[j] * scale + comp[tl * 16 + sl][h];
      scores[(size_t)((b * HH + h) * NS + t0 + tl) * NS + s0 + sl] = v;
    }
  }
}

// ---------------- softmax (fp32 in, bf16 out in-place) ----------------

__global__ void softmax_rows(float* __restrict__ sc) {
  int row = blockIdx.x;
  int tid = threadIdx.x;
  float* rp = sc + (size_t)row * NS;
  float v0 = rp[tid], v1 = rp[tid + 256];
  float m = fmaxf(v0, v1);
  #pragma unroll
  for (int o = 32; o; o >>= 1) m = fmaxf(m, __shfl_xor(m, o, 64));
  __shared__ float redm[4], reds[4];
  int lane = tid & 63, w = tid >> 6;
  if (!lane) redm[w] = m;
  __syncthreads();
  m = fmaxf(fmaxf(redm[0], redm[1]), fmaxf(redm[2], redm[3]));
  float e0 = __expf(v0 - m), e1 = __expf(v1 - m);
  float s = e0 + e1;
  #pragma unroll
  for (int o = 32; o; o >>= 1) s += __shfl_xor(s, o, 64);
  if (!lane) reds[w] = s;
  __syncthreads();
  s = (reds[0] + reds[1]) + (reds[2] + reds[3]);
  float r = 1.0f / s;
  u16* ar = (u16*)rp;
  ar[tid] = f2bf(e0 * r);
  ar[tid + 256] = f2bf(e1 * r);
}

// ---------------- PV: O = attn @ V ----------------

__global__ __launch_bounds__(256, 2) void pv_kernel(
    const u16* __restrict__ attn,   // bf16 packed in fp32-stride rows (1024 u16 per row)
    const u16* __restrict__ vT,     // [B,H,D,N]
    u16* __restrict__ attn_out) {   // [2048,1024] bf16
  const int ttile = blockIdx.x, h = blockIdx.y, b = blockIdx.z;
  const int tid = threadIdx.x, lane = tid & 63, wave = tid >> 6;
  const int t0 = (ttile << 6) + (wave << 4);
  const f32x4 zero = {0.f, 0.f, 0.f, 0.f};
  f32x4 acc[4];
  #pragma unroll
  for (int i = 0; i < 4; ++i) acc[i] = zero;
  const u16* abase = attn + (size_t)((b * HH + h) * NS + t0 + (lane & 15)) * 1024 + ((lane >> 4) << 3);
  const u16* vbase = vT + (size_t)((b * HH + h) * DD) * NS + ((lane >> 4) << 3);
  #pragma unroll 4
  for (int ks = 0; ks < 16; ++ks) {
    short8 a = *(const short8*)(abase + ks * 32);
    #pragma unroll
    for (int nf = 0; nf < 4; ++nf) {
      short8 vv = *(const short8*)(vbase + (size_t)(nf * 16 + (lane & 15)) * NS + ks * 32);
      acc[nf] = __builtin_amdgcn_mfma_f32_16x16x32_bf16(a, vv, acc[nf], 0, 0, 0);
    }
  }
  #pragma unroll
  for (int nf = 0; nf < 4; ++nf)
    #pragma unroll
    for (int j = 0; j < 4; ++j) {
      int t = t0 + ((lane >> 4) << 2) + j;
      int col = (h << 6) + nf * 16 + (lane & 15);
      attn_out[(size_t)(b * NS + t) * EE + col] = f2bf(acc[nf][j]);
    }
}

// ---------------- launch ----------------

extern "C" void kernel_launch(void* const* d_in, const int* in_sizes, int n_in,
                              void* d_out, int out_size, void* d_ws, size_t ws_size,
                              hipStream_t stream) {
  const float* query = (const float*)d_in[0];
  const float* key   = (const float*)d_in[1];
  const float* value = (const float*)d_in[2];
  const float* se    = (const float*)d_in[3];
  const float* Wq = (const float*)d_in[4];  const float* bq = (const float*)d_in[5];
  const float* Wk = (const float*)d_in[6];  const float* bk = (const float*)d_in[7];
  const float* Wv = (const float*)d_in[8];  const float* bv = (const float*)d_in[9];
  const float* Wo = (const float*)d_in[10]; const float* bo = (const float*)d_in[11];
  const float* W1 = (const float*)d_in[12]; const float* b1 = (const float*)d_in[13];
  const float* W2 = (const float*)d_in[14]; const float* b2 = (const float*)d_in[15];
  const float* W3 = (const float*)d_in[16]; const float* b3 = (const float*)d_in[17];
  const float* temps = (const float*)d_in[18];

  char* p = (char*)d_ws;
  auto alloc = [&](size_t bytes) { char* r = p; p += (bytes + 255) & ~(size_t)255; return r; };
  u16* qb  = (u16*)alloc((size_t)MM * EE * 2);
  u16* kb  = (u16*)alloc((size_t)MM * EE * 2);
  u16* vb  = (u16*)alloc((size_t)MM * EE * 2);
  u16* WqT = (u16*)alloc((size_t)EE * EE * 2);
  u16* WkT = (u16*)alloc((size_t)EE * EE * 2);
  u16* WvT = (u16*)alloc((size_t)EE * EE * 2);
  u16* WoT = (u16*)alloc((size_t)EE * EE * 2);
  u16* W2T = (u16*)alloc(4096 * 2);
  u16* W3T = (u16*)alloc(1024 * 2);
  u16* qp  = (u16*)alloc((size_t)MM * EE * 2);
  u16* kp  = (u16*)alloc((size_t)MM * EE * 2);
  u16* vp  = (u16*)alloc((size_t)MM * EE * 2);
  u16* vTb = (u16*)alloc((size_t)MM * EE * 2);
  float* hi = (float*)alloc((size_t)MM * 64 * 4);
  float* hj = (float*)alloc((size_t)MM * 64 * 4);
  float* scores = (float*)alloc((size_t)BB * HH * NS * NS * 4);
  u16* attn_out = (u16*)alloc((size_t)MM * EE * 2);
  (void)ws_size; (void)in_sizes; (void)n_in; (void)out_size;

  cvt_inputs<<<3072, 256, 0, stream>>>(query, key, value, qb, kb, vb);
  cvt_w<<<dim3(32, 32, 4), 256, 0, stream>>>(Wq, Wk, Wv, Wo, WqT, WkT, WvT, WoT);
  cvt_w_small<<<1, 256, 0, stream>>>(W2, W3, W2T, W3T);
  hi_hj_kernel<<<512, 256, 0, stream>>>(se, W1, b1, hi, hj);
  gemm_proj<<<dim3(16, 8, 3), 256, 0, stream>>>(qb, kb, vb, WqT, WkT, WvT, bq, bk, bv, qp, kp, vp);
  transpose_v<<<1024, 256, 0, stream>>>(vp, vTb);
  bias_scores<<<dim3(32, 32, 4), 256, 0, stream>>>(hi, hj, W2T, W3T, b2, b3, temps, qp, kp, scores);
  softmax_rows<<<BB * HH * NS, 256, 0, stream>>>(scores);
  pv_kernel<<<dim3(8, 16, 4), 256, 0, stream>>>((const u16*)scores, vTb, attn_out);
  gemm_final<<<dim3(16, 8, 1), 256, 0, stream>>>(attn_out, WoT, bo, (float*)d_out);
}

// Round 2
// 179.946 us; speedup vs baseline: 1.1993x; 1.1993x over previous
//
#include <hip/hip_runtime.h>
#include <hip/hip_bf16.h>

typedef unsigned short u16;
typedef short short8 __attribute__((ext_vector_type(8)));
typedef float f32x4 __attribute__((ext_vector_type(4)));
typedef unsigned short u16x8 __attribute__((ext_vector_type(8)));

#define BB 4
#define NS 512
#define EE 1024
#define HH 16
#define DD 64
#define MM (BB*NS)   // 2048

__device__ __forceinline__ u16 f2bf(float x) {
  union { float f; unsigned int u; } v; v.f = x;
  unsigned int r = v.u + 0x7fffu + ((v.u >> 16) & 1u);
  return (u16)(r >> 16);
}

__device__ __forceinline__ void gload_lds16(const void* g, void* l) {
  __builtin_amdgcn_global_load_lds(
      (const __attribute__((address_space(1))) unsigned int*)g,
      (__attribute__((address_space(3))) unsigned int*)l, 16, 0, 0);
}

// ---------------- converts ----------------

__global__ void cvt_inputs(const float* __restrict__ q, const float* __restrict__ k,
                           const float* __restrict__ v,
                           u16* __restrict__ qb, u16* __restrict__ kb, u16* __restrict__ vb) {
  size_t g = (size_t)blockIdx.x * 256 + threadIdx.x;
  size_t e = g << 3;                          // 8 elements / thread
  int seg = (int)(e >> 21);                   // 2048*1024 = 2^21 per tensor
  size_t off = e & ((1u << 21) - 1);
  const float* src = seg == 0 ? q : (seg == 1 ? k : v);
  u16* dst = seg == 0 ? qb : (seg == 1 ? kb : vb);
  float4 f0 = *(const float4*)(src + off);
  float4 f1 = *(const float4*)(src + off + 4);
  u16x8 r;
  r[0] = f2bf(f0.x); r[1] = f2bf(f0.y); r[2] = f2bf(f0.z); r[3] = f2bf(f0.w);
  r[4] = f2bf(f1.x); r[5] = f2bf(f1.y); r[6] = f2bf(f1.z); r[7] = f2bf(f1.w);
  *(u16x8*)(dst + off) = r;
}

__global__ void cvt_w(const float* __restrict__ Wq, const float* __restrict__ Wk,
                      const float* __restrict__ Wv, const float* __restrict__ Wo,
                      u16* __restrict__ WqT, u16* __restrict__ WkT,
                      u16* __restrict__ WvT, u16* __restrict__ WoT) {
  int z = blockIdx.z;
  const float* W = z == 0 ? Wq : z == 1 ? Wk : z == 2 ? Wv : Wo;
  u16* WT = z == 0 ? WqT : z == 1 ? WkT : z == 2 ? WvT : WoT;
  int n0 = blockIdx.x << 5, k0 = blockIdx.y << 5;
  __shared__ float tile[32][33];
  int tx = threadIdx.x & 31, ty = threadIdx.x >> 5;   // 32x8
  #pragma unroll
  for (int i = 0; i < 4; ++i) {
    int r = (i << 3) + ty;
    tile[r][tx] = W[(size_t)(k0 + r) * EE + n0 + tx];
  }
  __syncthreads();
  #pragma unroll
  for (int i = 0; i < 4; ++i) {
    int r = (i << 3) + ty;                            // n-local
    WT[(size_t)(n0 + r) * EE + k0 + tx] = f2bf(tile[tx][r]);
  }
}

__global__ void cvt_w_small(const float* __restrict__ W2, const float* __restrict__ W3,
                            u16* __restrict__ W2T, u16* __restrict__ W3P) {
  int tid = threadIdx.x;
  for (int i = tid; i < 4096; i += 256) {
    int n = i >> 6, k = i & 63;
    W2T[i] = f2bf(W2[k * 64 + n]);
  }
  // W3P: permuted so layer-3 A-fragment slot (g,j) of call k2 holds
  // W3[c][h] with c = (2*k2 + (j>=4))*16 + g*4 + (j&3)
  for (int i = tid; i < 1024; i += 256) {
    int h = i >> 6, rem = i & 63;
    int k2 = rem >> 5, gg = (rem >> 3) & 3, j = rem & 7;
    int c = (2 * k2 + (j >> 2)) * 16 + gg * 4 + (j & 3);
    W3P[i] = f2bf(W3[c * 16 + h]);
  }
}

// ---------------- hi / hj ----------------

__global__ void hi_hj_kernel(const float* __restrict__ se, const float* __restrict__ W1,
                             const float* __restrict__ b1,
                             float* __restrict__ hi, float* __restrict__ hj) {
  int tid = threadIdx.x;
  int row = blockIdx.x * 4 + (tid >> 6);
  int c = tid & 63;
  float ah = b1[c], aj = 0.f;
  #pragma unroll 8
  for (int k = 0; k < 64; ++k) {
    float s = se[row * 64 + k];
    ah += s * W1[k * 64 + c];
    aj += s * W1[(k + 64) * 64 + c];
  }
  hi[row * 64 + c] = ah;   // b1 folded into hi
  hj[row * 64 + c] = aj;
}

// ---------------- main GEMM (M x 1024 @ 1024 x 1024, Bt = [N][K]) ----------------

template <bool F32OUT>
__device__ __forceinline__ void gemm_body(const u16* __restrict__ A, const u16* __restrict__ Bt,
                                          const float* __restrict__ bias, void* __restrict__ Cout) {
  __shared__ u16 As[128 * 32];
  __shared__ u16 Bs[128 * 32];
  const int tid = threadIdx.x, lane = tid & 63, wave = tid >> 6;
  const int m0 = blockIdx.x * 128, n0 = blockIdx.y * 128;
  const int wr = wave >> 1, wc = wave & 1;

  const f32x4 zero = {0.f, 0.f, 0.f, 0.f};
  f32x4 acc[4][4];
  #pragma unroll
  for (int i = 0; i < 4; ++i)
    #pragma unroll
    for (int j = 0; j < 4; ++j) acc[i][j] = zero;

  const int rA = lane >> 2;            // row within 16-row chunk
  const int cA = (lane & 3) << 3;      // k sub-offset (elements)

  for (int kt = 0; kt < EE; kt += 32) {
    #pragma unroll
    for (int i = 0; i < 2; ++i) {
      int base = ((i << 2) + wave) << 9;           // element offset of wave chunk
      int row = (base >> 5) + rA;
      gload_lds16(A  + (size_t)(m0 + row) * EE + kt + cA, As + base);
      gload_lds16(Bt + (size_t)(n0 + row) * EE + kt + cA, Bs + base);
    }
    __syncthreads();
    short8 af[4], bfr[4];
    #pragma unroll
    for (int mf = 0; mf < 4; ++mf) {
      int row = wr * 64 + mf * 16 + (lane & 15);
      af[mf] = *(const short8*)(As + row * 32 + ((lane >> 4) << 3));
    }
    #pragma unroll
    for (int nf = 0; nf < 4; ++nf) {
      int row = wc * 64 + nf * 16 + (lane & 15);
      bfr[nf] = *(const short8*)(Bs + row * 32 + ((lane >> 4) << 3));
    }
    #pragma unroll
    for (int mf = 0; mf < 4; ++mf)
      #pragma unroll
      for (int nf = 0; nf < 4; ++nf)
        acc[mf][nf] = __builtin_amdgcn_mfma_f32_16x16x32_bf16(af[mf], bfr[nf], acc[mf][nf], 0, 0, 0);
    __syncthreads();
  }

  #pragma unroll
  for (int mf = 0; mf < 4; ++mf) {
    #pragma unroll
    for (int nf = 0; nf < 4; ++nf) {
      int col = n0 + wc * 64 + nf * 16 + (lane & 15);
      float bv = bias[col];
      #pragma unroll
      for (int j = 0; j < 4; ++j) {
        int rowm = m0 + wr * 64 + mf * 16 + ((lane >> 4) << 2) + j;
        float v = acc[mf][nf][j] + bv;
        if (F32OUT) ((float*)Cout)[(size_t)rowm * EE + col] = v;
        else        ((u16*)Cout)[(size_t)rowm * EE + col] = f2bf(v);
      }
    }
  }
}

__global__ __launch_bounds__(256, 2) void gemm_proj(
    const u16* __restrict__ qb, const u16* __restrict__ kb, const u16* __restrict__ vb,
    const u16* __restrict__ WqT, const u16* __restrict__ WkT, const u16* __restrict__ WvT,
    const float* __restrict__ bq, const float* __restrict__ bk, const float* __restrict__ bv_,
    u16* __restrict__ qp, u16* __restrict__ kp, u16* __restrict__ vp) {
  int z = blockIdx.z;
  const u16* A = z == 0 ? qb : (z == 1 ? kb : vb);
  const u16* Bt = z == 0 ? WqT : (z == 1 ? WkT : WvT);
  const float* bias = z == 0 ? bq : (z == 1 ? bk : bv_);
  u16* C = z == 0 ? qp : (z == 1 ? kp : vp);
  gemm_body<false>(A, Bt, bias, C);
}

__global__ __launch_bounds__(256, 2) void gemm_final(
    const u16* __restrict__ A, const u16* __restrict__ WoT,
    const float* __restrict__ bo, float* __restrict__ C) {
  gemm_body<true>(A, WoT, bo, C);
}

// ---------------- transpose V: [B,N,H,D] -> [B,H,D,N] ----------------

__global__ void transpose_v(const u16* __restrict__ vp, u16* __restrict__ vT) {
  int id = blockIdx.x;               // b*256 + h*16 + ntile
  int b = id >> 8, rem = id & 255, h = rem >> 4, nt = rem & 15;
  int n0 = nt << 5;
  __shared__ u16 tile[32][72];
  int tid = threadIdx.x;
  int tx = tid & 63, ty = tid >> 6;
  #pragma unroll
  for (int i = 0; i < 8; ++i) {
    int r = (i << 2) + ty;
    tile[r][tx] = vp[(size_t)(b * NS + n0 + r) * EE + (h << 6) + tx];
  }
  __syncthreads();
  int nl = tid & 31, dsub = tid >> 5;   // dsub 0..7
  #pragma unroll
  for (int i = 0; i < 8; ++i) {
    int d = (i << 3) + dsub;
    vT[(size_t)((b * HH + h) * DD + d) * NS + n0 + nl] = tile[nl][d];
  }
}

// ---------------- fused CAB-bias MLP + QK^T -> scores (register-resident MLP) --------

__global__ __launch_bounds__(256, 3) void bias_scores(
    const float* __restrict__ hi, const float* __restrict__ hj,
    const u16* __restrict__ W2T, const u16* __restrict__ W3P,
    const float* __restrict__ b2, const float* __restrict__ b3,
    const float* __restrict__ temps,
    const u16* __restrict__ qp, const u16* __restrict__ kp,
    float* __restrict__ scores) {
  const int st = blockIdx.x, tt = blockIdx.y, b = blockIdx.z;
  const int t0 = tt << 4, s0 = st << 4;
  const int tid = threadIdx.x, lane = tid & 63, wave = tid >> 6;
  const int g = lane >> 4, sl = lane & 15;

  __shared__ float hi_s[16][80];      // b128 broadcast reads (row uniform per fragment)
  __shared__ float hj_s[16][65];      // scalar reads, stride 65 -> 2-way (free)
  __shared__ float b2_s[64];
  __shared__ float b3_s[16], tp_s[16];
  __shared__ float comp_s[256][20];   // pair x head bias, f32

  // ---- stage hi/hj tile rows + small vectors ----
  {
    int r = tid >> 4, c4 = (tid & 15) << 2;
    float4 hv = *(const float4*)(hi + ((size_t)(b * NS + t0 + r) << 6) + c4);
    *(f32x4*)&hi_s[r][c4] = (f32x4){hv.x, hv.y, hv.z, hv.w};
    float4 jv = *(const float4*)(hj + ((size_t)(b * NS + s0 + r) << 6) + c4);
    hj_s[r][c4] = jv.x; hj_s[r][c4 + 1] = jv.y; hj_s[r][c4 + 2] = jv.z; hj_s[r][c4 + 3] = jv.w;
    if (tid < 64) b2_s[tid] = b2[tid];
    else if (tid < 80) b3_s[tid - 64] = b3[tid - 64];
    else if (tid < 96) tp_s[tid - 80] = temps[tid - 80];
  }
  __syncthreads();

  // ---- layer-2 B-fragments (X rows p) built directly in registers ----
  float hjv[2][8];                    // this lane's hj values, reused across all 4 fragments
  #pragma unroll
  for (int kk = 0; kk < 2; ++kk)
    #pragma unroll
    for (int j = 0; j < 8; ++j)
      hjv[kk][j] = hj_s[sl][kk * 32 + (g << 3) + j];

  short8 xb[4][2];
  #pragma unroll
  for (int mfp = 0; mfp < 4; ++mfp) {
    int tl = (wave << 2) + mfp;       // uniform across lanes
    #pragma unroll
    for (int kk = 0; kk < 2; ++kk) {
      int c0 = kk * 32 + (g << 3);
      f32x4 h0 = *(const f32x4*)&hi_s[tl][c0];
      f32x4 h1 = *(const f32x4*)&hi_s[tl][c0 + 4];
      short8 r;
      #pragma unroll
      for (int j = 0; j < 4; ++j) {
        r[j]     = (short)f2bf(fmaxf(h0[j] + hjv[kk][j], 0.f));
        r[j + 4] = (short)f2bf(fmaxf(h1[j] + hjv[kk][j + 4], 0.f));
      }
      xb[mfp][kk] = r;
    }
  }

  // ---- layer 2 (transposed): accY[c][p] = W2T-frags x X-frags ----
  short8 w2f[4][2];
  #pragma unroll
  for (int mfc = 0; mfc < 4; ++mfc)
    #pragma unroll
    for (int kk = 0; kk < 2; ++kk)
      w2f[mfc][kk] = *(const short8*)(W2T + ((mfc * 16 + sl) << 6) + kk * 32 + (g << 3));

  const f32x4 zero = {0.f, 0.f, 0.f, 0.f};
  f32x4 accY[4][4];
  #pragma unroll
  for (int i = 0; i < 4; ++i)
    #pragma unroll
    for (int j = 0; j < 4; ++j) accY[i][j] = zero;
  #pragma unroll
  for (int kk = 0; kk < 2; ++kk)
    #pragma unroll
    for (int mfc = 0; mfc < 4; ++mfc)
      #pragma unroll
      for (int nfp = 0; nfp < 4; ++nfp)
        accY[mfc][nfp] = __builtin_amdgcn_mfma_f32_16x16x32_bf16(w2f[mfc][kk], xb[nfp][kk], accY[mfc][nfp], 0, 0, 0);

  // ---- layer 3: repack Y^T acc (bias+relu+bf16) into B-fragments, custom k-order ----
  float b2v[4][4];
  #pragma unroll
  for (int mfc = 0; mfc < 4; ++mfc)
    #pragma unroll
    for (int jj = 0; jj < 4; ++jj)
      b2v[mfc][jj] = b2_s[mfc * 16 + (g << 2) + jj];

  short8 w3f[2];
  #pragma unroll
  for (int k2 = 0; k2 < 2; ++k2)
    w3f[k2] = *(const short8*)(W3P + (sl << 6) + k2 * 32 + (g << 3));

  f32x4 compD[4];
  #pragma unroll
  for (int i = 0; i < 4; ++i) compD[i] = zero;
  #pragma unroll
  for (int k2 = 0; k2 < 2; ++k2) {
    #pragma unroll
    for (int nfp = 0; nfp < 4; ++nfp) {
      short8 y;
      #pragma unroll
      for (int j = 0; j < 4; ++j) {
        y[j]     = (short)f2bf(fmaxf(accY[2 * k2][nfp][j]     + b2v[2 * k2][j],     0.f));
        y[j + 4] = (short)f2bf(fmaxf(accY[2 * k2 + 1][nfp][j] + b2v[2 * k2 + 1][j], 0.f));
      }
      compD[nfp] = __builtin_amdgcn_mfma_f32_16x16x32_bf16(w3f[k2], y, compD[nfp], 0, 0, 0);
    }
  }

  // ---- comp -> LDS (b128, 2-way free) ----
  #pragma unroll
  for (int nfp = 0; nfp < 4; ++nfp) {
    f32x4 cv;
    #pragma unroll
    for (int jj = 0; jj < 4; ++jj) {
      int h = (g << 2) + jj;
      cv[jj] = (compD[nfp][jj] + b3_s[h]) * tp_s[h];
    }
    *(f32x4*)&comp_s[(wave << 6) + nfp * 16 + sl][g << 2] = cv;
  }
  __syncthreads();

  // ---- QK^T + bias; wave handles heads 4*wave..4*wave+3 ----
  const float scale = 0.125f;
  #pragma unroll
  for (int hh = 0; hh < 4; ++hh) {
    int h = (wave << 2) + hh;
    short8 aq[2], bk_[2];
    #pragma unroll
    for (int kk = 0; kk < 2; ++kk) {
      aq[kk]  = *(const short8*)(qp + (size_t)(b * NS + t0 + sl) * EE + (h << 6) + kk * 32 + (g << 3));
      bk_[kk] = *(const short8*)(kp + (size_t)(b * NS + s0 + sl) * EE + (h << 6) + kk * 32 + (g << 3));
    }
    f32x4 accS = zero;
    accS = __builtin_amdgcn_mfma_f32_16x16x32_bf16(aq[0], bk_[0], accS, 0, 0, 0);
    accS = __builtin_amdgcn_mfma_f32_16x16x32_bf16(aq[1], bk_[1], accS, 0, 0, 0);
    #pragma unroll
    for (int j = 0; j < 4; ++j) {
      int tl = (g << 2) + j;
      float v = accS[j] * scale + comp_s[tl * 16 + sl][h];
      scores[(size_t)((b * HH + h) * NS + t0 + tl) * NS + s0 + sl] = v;
    }
  }
}

// ---------------- softmax (fp32 in, bf16 out in-place) ----------------

__global__ void softmax_rows(float* __restrict__ sc) {
  int row = blockIdx.x;
  int tid = threadIdx.x;
  float* rp = sc + (size_t)row * NS;
  float v0 = rp[tid], v1 = rp[tid + 256];
  float m = fmaxf(v0, v1);
  #pragma unroll
  for (int o = 32; o; o >>= 1) m = fmaxf(m, __shfl_xor(m, o, 64));
  __shared__ float redm[4], reds[4];
  int lane = tid & 63, w = tid >> 6;
  if (!lane) redm[w] = m;
  __syncthreads();
  m = fmaxf(fmaxf(redm[0], redm[1]), fmaxf(redm[2], redm[3]));
  float e0 = __expf(v0 - m), e1 = __expf(v1 - m);
  float s = e0 + e1;
  #pragma unroll
  for (int o = 32; o; o >>= 1) s += __shfl_xor(s, o, 64);
  if (!lane) reds[w] = s;
  __syncthreads();
  s = (reds[0] + reds[1]) + (reds[2] + reds[3]);
  float r = 1.0f / s;
  u16* ar = (u16*)rp;
  ar[tid] = f2bf(e0 * r);
  ar[tid + 256] = f2bf(e1 * r);
}

// ---------------- PV: O = attn @ V ----------------

__global__ __launch_bounds__(256, 2) void pv_kernel(
    const u16* __restrict__ attn,   // bf16 packed in fp32-stride rows (1024 u16 per row)
    const u16* __restrict__ vT,     // [B,H,D,N]
    u16* __restrict__ attn_out) {   // [2048,1024] bf16
  const int ttile = blockIdx.x, h = blockIdx.y, b = blockIdx.z;
  const int tid = threadIdx.x, lane = tid & 63, wave = tid >> 6;
  const int t0 = (ttile << 6) + (wave << 4);
  const f32x4 zero = {0.f, 0.f, 0.f, 0.f};
  f32x4 acc[4];
  #pragma unroll
  for (int i = 0; i < 4; ++i) acc[i] = zero;
  const u16* abase = attn + (size_t)((b * HH + h) * NS + t0 + (lane & 15)) * 1024 + ((lane >> 4) << 3);
  const u16* vbase = vT + (size_t)((b * HH + h) * DD) * NS + ((lane >> 4) << 3);
  #pragma unroll 4
  for (int ks = 0; ks < 16; ++ks) {
    short8 a = *(const short8*)(abase + ks * 32);
    #pragma unroll
    for (int nf = 0; nf < 4; ++nf) {
      short8 vv = *(const short8*)(vbase + (size_t)(nf * 16 + (lane & 15)) * NS + ks * 32);
      acc[nf] = __builtin_amdgcn_mfma_f32_16x16x32_bf16(a, vv, acc[nf], 0, 0, 0);
    }
  }
  #pragma unroll
  for (int nf = 0; nf < 4; ++nf)
    #pragma unroll
    for (int j = 0; j < 4; ++j) {
      int t = t0 + ((lane >> 4) << 2) + j;
      int col = (h << 6) + nf * 16 + (lane & 15);
      attn_out[(size_t)(b * NS + t) * EE + col] = f2bf(acc[nf][j]);
    }
}

// ---------------- launch ----------------

extern "C" void kernel_launch(void* const* d_in, const int* in_sizes, int n_in,
                              void* d_out, int out_size, void* d_ws, size_t ws_size,
                              hipStream_t stream) {
  const float* query = (const float*)d_in[0];
  const float* key   = (const float*)d_in[1];
  const float* value = (const float*)d_in[2];
  const float* se    = (const float*)d_in[3];
  const float* Wq = (const float*)d_in[4];  const float* bq = (const float*)d_in[5];
  const float* Wk = (const float*)d_in[6];  const float* bk = (const float*)d_in[7];
  const float* Wv = (const float*)d_in[8];  const float* bv = (const float*)d_in[9];
  const float* Wo = (const float*)d_in[10]; const float* bo = (const float*)d_in[11];
  const float* W1 = (const float*)d_in[12]; const float* b1 = (const float*)d_in[13];
  const float* W2 = (const float*)d_in[14]; const float* b2 = (const float*)d_in[15];
  const float* W3 = (const float*)d_in[16]; const float* b3 = (const float*)d_in[17];
  const float* temps = (const float*)d_in[18];

  char* p = (char*)d_ws;
  auto alloc = [&](size_t bytes) { char* r = p; p += (bytes + 255) & ~(size_t)255; return r; };
  u16* qb  = (u16*)alloc((size_t)MM * EE * 2);
  u16* kb  = (u16*)alloc((size_t)MM * EE * 2);
  u16* vb  = (u16*)alloc((size_t)MM * EE * 2);
  u16* WqT = (u16*)alloc((size_t)EE * EE * 2);
  u16* WkT = (u16*)alloc((size_t)EE * EE * 2);
  u16* WvT = (u16*)alloc((size_t)EE * EE * 2);
  u16* WoT = (u16*)alloc((size_t)EE * EE * 2);
  u16* W2T = (u16*)alloc(4096 * 2);
  u16* W3P = (u16*)alloc(1024 * 2);
  u16* qp  = (u16*)alloc((size_t)MM * EE * 2);
  u16* kp  = (u16*)alloc((size_t)MM * EE * 2);
  u16* vp  = (u16*)alloc((size_t)MM * EE * 2);
  u16* vTb = (u16*)alloc((size_t)MM * EE * 2);
  float* hi = (float*)alloc((size_t)MM * 64 * 4);
  float* hj = (float*)alloc((size_t)MM * 64 * 4);
  float* scores = (float*)alloc((size_t)BB * HH * NS * NS * 4);
  u16* attn_out = (u16*)alloc((size_t)MM * EE * 2);
  (void)ws_size; (void)in_sizes; (void)n_in; (void)out_size;

  cvt_inputs<<<3072, 256, 0, stream>>>(query, key, value, qb, kb, vb);
  cvt_w<<<dim3(32, 32, 4), 256, 0, stream>>>(Wq, Wk, Wv, Wo, WqT, WkT, WvT, WoT);
  cvt_w_small<<<1, 256, 0, stream>>>(W2, W3, W2T, W3P);
  hi_hj_kernel<<<512, 256, 0, stream>>>(se, W1, b1, hi, hj);
  gemm_proj<<<dim3(16, 8, 3), 256, 0, stream>>>(qb, kb, vb, WqT, WkT, WvT, bq, bk, bv, qp, kp, vp);
  transpose_v<<<1024, 256, 0, stream>>>(vp, vTb);
  bias_scores<<<dim3(32, 32, 4), 256, 0, stream>>>(hi, hj, W2T, W3P, b2, b3, temps, qp, kp, scores);
  softmax_rows<<<BB * HH * NS, 256, 0, stream>>>(scores);
  pv_kernel<<<dim3(8, 16, 4), 256, 0, stream>>>((const u16*)scores, vTb, attn_out);
  gemm_final<<<dim3(16, 8, 1), 256, 0, stream>>>(attn_out, WoT, bo, (float*)d_out);
}

// Round 3
// 177.475 us; speedup vs baseline: 1.2160x; 1.0139x over previous
//
#include <hip/hip_runtime.h>
#include <hip/hip_bf16.h>

typedef unsigned short u16;
typedef short short8 __attribute__((ext_vector_type(8)));
typedef float f32x4 __attribute__((ext_vector_type(4)));
typedef unsigned short u16x8 __attribute__((ext_vector_type(8)));

#define BB 4
#define NS 512
#define EE 1024
#define HH 16
#define DD 64
#define MM (BB*NS)   // 2048

__device__ __forceinline__ u16 f2bf(float x) {
  union { float f; unsigned int u; } v; v.f = x;
  unsigned int r = v.u + 0x7fffu + ((v.u >> 16) & 1u);
  return (u16)(r >> 16);
}

// hardware-converted bf16 (compiler emits v_cvt_pk_bf16_f32 for pairs)
__device__ __forceinline__ u16 f2bfh(float x) {
  __hip_bfloat16 h = __float2bfloat16(x);
  union { __hip_bfloat16 h; u16 u; } c; c.h = h; return c.u;
}
__device__ __forceinline__ unsigned pkbf(float a, float b) {
  union { __hip_bfloat16 h; u16 u; } ca, cb;
  ca.h = __float2bfloat16(a); cb.h = __float2bfloat16(b);
  return (unsigned)ca.u | ((unsigned)cb.u << 16);
}
union S8 { short8 s; unsigned u[4]; };

__device__ __forceinline__ void gload_lds16(const void* g, void* l) {
  __builtin_amdgcn_global_load_lds(
      (const __attribute__((address_space(1))) unsigned int*)g,
      (__attribute__((address_space(3))) unsigned int*)l, 16, 0, 0);
}

// ---------------- converts ----------------

__global__ void cvt_inputs(const float* __restrict__ q, const float* __restrict__ k,
                           const float* __restrict__ v,
                           u16* __restrict__ qb, u16* __restrict__ kb, u16* __restrict__ vb) {
  size_t g = (size_t)blockIdx.x * 256 + threadIdx.x;
  size_t e = g << 3;                          // 8 elements / thread
  int seg = (int)(e >> 21);                   // 2048*1024 = 2^21 per tensor
  size_t off = e & ((1u << 21) - 1);
  const float* src = seg == 0 ? q : (seg == 1 ? k : v);
  u16* dst = seg == 0 ? qb : (seg == 1 ? kb : vb);
  float4 f0 = *(const float4*)(src + off);
  float4 f1 = *(const float4*)(src + off + 4);
  S8 r;
  r.u[0] = pkbf(f0.x, f0.y); r.u[1] = pkbf(f0.z, f0.w);
  r.u[2] = pkbf(f1.x, f1.y); r.u[3] = pkbf(f1.z, f1.w);
  *(short8*)(dst + off) = r.s;
}

__global__ void cvt_w(const float* __restrict__ Wq, const float* __restrict__ Wk,
                      const float* __restrict__ Wv, const float* __restrict__ Wo,
                      u16* __restrict__ WqT, u16* __restrict__ WkT,
                      u16* __restrict__ WvT, u16* __restrict__ WoT) {
  int z = blockIdx.z;
  const float* W = z == 0 ? Wq : z == 1 ? Wk : z == 2 ? Wv : Wo;
  u16* WT = z == 0 ? WqT : z == 1 ? WkT : z == 2 ? WvT : WoT;
  int n0 = blockIdx.x << 5, k0 = blockIdx.y << 5;
  __shared__ float tile[32][33];
  int tx = threadIdx.x & 31, ty = threadIdx.x >> 5;   // 32x8
  #pragma unroll
  for (int i = 0; i < 4; ++i) {
    int r = (i << 3) + ty;
    tile[r][tx] = W[(size_t)(k0 + r) * EE + n0 + tx];
  }
  __syncthreads();
  #pragma unroll
  for (int i = 0; i < 4; ++i) {
    int r = (i << 3) + ty;                            // n-local
    WT[(size_t)(n0 + r) * EE + k0 + tx] = f2bfh(tile[tx][r]);
  }
}

__global__ void cvt_w_small(const float* __restrict__ W2, const float* __restrict__ W3,
                            u16* __restrict__ W2T, u16* __restrict__ W3P) {
  int tid = threadIdx.x;
  for (int i = tid; i < 4096; i += 256) {
    int n = i >> 6, k = i & 63;
    W2T[i] = f2bfh(W2[k * 64 + n]);
  }
  // W3P: permuted so layer-3 A-fragment slot (g,j) of call k2 holds
  // W3[c][h] with c = (2*k2 + (j>=4))*16 + g*4 + (j&3)
  for (int i = tid; i < 1024; i += 256) {
    int h = i >> 6, rem = i & 63;
    int k2 = rem >> 5, gg = (rem >> 3) & 3, j = rem & 7;
    int c = (2 * k2 + (j >> 2)) * 16 + gg * 4 + (j & 3);
    W3P[i] = f2bfh(W3[c * 16 + h]);
  }
}

// ---------------- hi / hj ----------------

__global__ void hi_hj_kernel(const float* __restrict__ se, const float* __restrict__ W1,
                             const float* __restrict__ b1,
                             float* __restrict__ hi, float* __restrict__ hj) {
  int tid = threadIdx.x;
  int row = blockIdx.x * 4 + (tid >> 6);
  int c = tid & 63;
  float ah = b1[c], aj = 0.f;
  #pragma unroll 8
  for (int k = 0; k < 64; ++k) {
    float s = se[row * 64 + k];
    ah += s * W1[k * 64 + c];
    aj += s * W1[(k + 64) * 64 + c];
  }
  hi[row * 64 + c] = ah;   // b1 folded into hi
  hj[row * 64 + c] = aj;
}

// ---------------- main GEMM (M x 1024 @ 1024 x 1024, Bt = [N][K]) ----------------

template <bool F32OUT>
__device__ __forceinline__ void gemm_body(const u16* __restrict__ A, const u16* __restrict__ Bt,
                                          const float* __restrict__ bias, void* __restrict__ Cout) {
  __shared__ u16 As[128 * 32];
  __shared__ u16 Bs[128 * 32];
  const int tid = threadIdx.x, lane = tid & 63, wave = tid >> 6;
  const int m0 = blockIdx.x * 128, n0 = blockIdx.y * 128;
  const int wr = wave >> 1, wc = wave & 1;

  const f32x4 zero = {0.f, 0.f, 0.f, 0.f};
  f32x4 acc[4][4];
  #pragma unroll
  for (int i = 0; i < 4; ++i)
    #pragma unroll
    for (int j = 0; j < 4; ++j) acc[i][j] = zero;

  const int rA = lane >> 2;            // row within 16-row chunk
  const int cA = (lane & 3) << 3;      // k sub-offset (elements)

  for (int kt = 0; kt < EE; kt += 32) {
    #pragma unroll
    for (int i = 0; i < 2; ++i) {
      int base = ((i << 2) + wave) << 9;           // element offset of wave chunk
      int row = (base >> 5) + rA;
      gload_lds16(A  + (size_t)(m0 + row) * EE + kt + cA, As + base);
      gload_lds16(Bt + (size_t)(n0 + row) * EE + kt + cA, Bs + base);
    }
    __syncthreads();
    short8 af[4], bfr[4];
    #pragma unroll
    for (int mf = 0; mf < 4; ++mf) {
      int row = wr * 64 + mf * 16 + (lane & 15);
      af[mf] = *(const short8*)(As + row * 32 + ((lane >> 4) << 3));
    }
    #pragma unroll
    for (int nf = 0; nf < 4; ++nf) {
      int row = wc * 64 + nf * 16 + (lane & 15);
      bfr[nf] = *(const short8*)(Bs + row * 32 + ((lane >> 4) << 3));
    }
    #pragma unroll
    for (int mf = 0; mf < 4; ++mf)
      #pragma unroll
      for (int nf = 0; nf < 4; ++nf)
        acc[mf][nf] = __builtin_amdgcn_mfma_f32_16x16x32_bf16(af[mf], bfr[nf], acc[mf][nf], 0, 0, 0);
    __syncthreads();
  }

  #pragma unroll
  for (int mf = 0; mf < 4; ++mf) {
    #pragma unroll
    for (int nf = 0; nf < 4; ++nf) {
      int col = n0 + wc * 64 + nf * 16 + (lane & 15);
      float bv = bias[col];
      #pragma unroll
      for (int j = 0; j < 4; ++j) {
        int rowm = m0 + wr * 64 + mf * 16 + ((lane >> 4) << 2) + j;
        float v = acc[mf][nf][j] + bv;
        if (F32OUT) ((float*)Cout)[(size_t)rowm * EE + col] = v;
        else        ((u16*)Cout)[(size_t)rowm * EE + col] = f2bfh(v);
      }
    }
  }
}

__global__ __launch_bounds__(256, 2) void gemm_proj(
    const u16* __restrict__ qb, const u16* __restrict__ kb, const u16* __restrict__ vb,
    const u16* __restrict__ WqT, const u16* __restrict__ WkT, const u16* __restrict__ WvT,
    const float* __restrict__ bq, const float* __restrict__ bk, const float* __restrict__ bv_,
    u16* __restrict__ qp, u16* __restrict__ kp, u16* __restrict__ vp) {
  int z = blockIdx.z;
  const u16* A = z == 0 ? qb : (z == 1 ? kb : vb);
  const u16* Bt = z == 0 ? WqT : (z == 1 ? WkT : WvT);
  const float* bias = z == 0 ? bq : (z == 1 ? bk : bv_);
  u16* C = z == 0 ? qp : (z == 1 ? kp : vp);
  gemm_body<false>(A, Bt, bias, C);
}

__global__ __launch_bounds__(256, 2) void gemm_final(
    const u16* __restrict__ A, const u16* __restrict__ WoT,
    const float* __restrict__ bo, float* __restrict__ C) {
  gemm_body<true>(A, WoT, bo, C);
}

// ---------------- transpose V: [B,N,H,D] -> [B,H,D,N] ----------------

__global__ void transpose_v(const u16* __restrict__ vp, u16* __restrict__ vT) {
  int id = blockIdx.x;               // b*256 + h*16 + ntile
  int b = id >> 8, rem = id & 255, h = rem >> 4, nt = rem & 15;
  int n0 = nt << 5;
  __shared__ u16 tile[32][72];
  int tid = threadIdx.x;
  int tx = tid & 63, ty = tid >> 6;
  #pragma unroll
  for (int i = 0; i < 8; ++i) {
    int r = (i << 2) + ty;
    tile[r][tx] = vp[(size_t)(b * NS + n0 + r) * EE + (h << 6) + tx];
  }
  __syncthreads();
  int nl = tid & 31, dsub = tid >> 5;   // dsub 0..7
  #pragma unroll
  for (int i = 0; i < 8; ++i) {
    int d = (i << 3) + dsub;
    vT[(size_t)((b * HH + h) * DD + d) * NS + n0 + nl] = tile[nl][d];
  }
}

// ---------------- fused CAB-bias MLP + QK^T -> scores (register-resident MLP) --------

__global__ __launch_bounds__(256, 5) void bias_scores(
    const float* __restrict__ hi, const float* __restrict__ hj,
    const u16* __restrict__ W2T, const u16* __restrict__ W3P,
    const float* __restrict__ b2, const float* __restrict__ b3,
    const float* __restrict__ temps,
    const u16* __restrict__ qp, const u16* __restrict__ kp,
    float* __restrict__ scores) {
  const int st = blockIdx.x, tt = blockIdx.y, b = blockIdx.z;
  const int t0 = tt << 4, s0 = st << 4;
  const int tid = threadIdx.x, lane = tid & 63, wave = tid >> 6;
  const int g = lane >> 4, sl = lane & 15;

  __shared__ float hi_s[16][80];      // b128 broadcast reads (row uniform per fragment)
  __shared__ float hj_s[16][65];      // scalar reads, stride 65 -> 2-way (free)
  __shared__ float b2_s[64];
  __shared__ float b3_s[16], tp_s[16];
  __shared__ float comp_s[256][20];   // pair x head bias, f32

  // ---- stage hi/hj tile rows + small vectors ----
  {
    int r = tid >> 4, c4 = (tid & 15) << 2;
    float4 hv = *(const float4*)(hi + ((size_t)(b * NS + t0 + r) << 6) + c4);
    *(f32x4*)&hi_s[r][c4] = (f32x4){hv.x, hv.y, hv.z, hv.w};
    float4 jv = *(const float4*)(hj + ((size_t)(b * NS + s0 + r) << 6) + c4);
    hj_s[r][c4] = jv.x; hj_s[r][c4 + 1] = jv.y; hj_s[r][c4 + 2] = jv.z; hj_s[r][c4 + 3] = jv.w;
    if (tid < 64) b2_s[tid] = b2[tid];
    else if (tid < 80) b3_s[tid - 64] = b3[tid - 64];
    else if (tid < 96) tp_s[tid - 80] = temps[tid - 80];
  }
  __syncthreads();

  // ---- layer-2 B-fragments (X rows p) built directly in registers ----
  float hjv[2][8];                    // this lane's hj values, reused across all 4 fragments
  #pragma unroll
  for (int kk = 0; kk < 2; ++kk)
    #pragma unroll
    for (int j = 0; j < 8; ++j)
      hjv[kk][j] = hj_s[sl][kk * 32 + (g << 3) + j];

  short8 xb[4][2];
  #pragma unroll
  for (int mfp = 0; mfp < 4; ++mfp) {
    int tl = (wave << 2) + mfp;       // uniform across lanes
    #pragma unroll
    for (int kk = 0; kk < 2; ++kk) {
      int c0 = kk * 32 + (g << 3);
      f32x4 h0 = *(const f32x4*)&hi_s[tl][c0];
      f32x4 h1 = *(const f32x4*)&hi_s[tl][c0 + 4];
      float x[8];
      #pragma unroll
      for (int j = 0; j < 4; ++j) {
        x[j]     = fmaxf(h0[j] + hjv[kk][j], 0.f);
        x[j + 4] = fmaxf(h1[j] + hjv[kk][j + 4], 0.f);
      }
      S8 r;
      r.u[0] = pkbf(x[0], x[1]); r.u[1] = pkbf(x[2], x[3]);
      r.u[2] = pkbf(x[4], x[5]); r.u[3] = pkbf(x[6], x[7]);
      xb[mfp][kk] = r.s;
    }
  }

  // ---- layer 2 (transposed): accY[c][p] = W2T-frags x X-frags ----
  short8 w2f[4][2];
  #pragma unroll
  for (int mfc = 0; mfc < 4; ++mfc)
    #pragma unroll
    for (int kk = 0; kk < 2; ++kk)
      w2f[mfc][kk] = *(const short8*)(W2T + ((mfc * 16 + sl) << 6) + kk * 32 + (g << 3));

  const f32x4 zero = {0.f, 0.f, 0.f, 0.f};
  f32x4 accY[4][4];
  #pragma unroll
  for (int i = 0; i < 4; ++i)
    #pragma unroll
    for (int j = 0; j < 4; ++j) accY[i][j] = zero;
  #pragma unroll
  for (int kk = 0; kk < 2; ++kk)
    #pragma unroll
    for (int mfc = 0; mfc < 4; ++mfc)
      #pragma unroll
      for (int nfp = 0; nfp < 4; ++nfp)
        accY[mfc][nfp] = __builtin_amdgcn_mfma_f32_16x16x32_bf16(w2f[mfc][kk], xb[nfp][kk], accY[mfc][nfp], 0, 0, 0);

  // ---- layer 3: repack Y^T acc (bias+relu+bf16) into B-fragments, custom k-order ----
  float b2v[4][4];
  #pragma unroll
  for (int mfc = 0; mfc < 4; ++mfc)
    #pragma unroll
    for (int jj = 0; jj < 4; ++jj)
      b2v[mfc][jj] = b2_s[mfc * 16 + (g << 2) + jj];

  short8 w3f[2];
  #pragma unroll
  for (int k2 = 0; k2 < 2; ++k2)
    w3f[k2] = *(const short8*)(W3P + (sl << 6) + k2 * 32 + (g << 3));

  f32x4 compD[4];
  #pragma unroll
  for (int i = 0; i < 4; ++i) compD[i] = zero;
  #pragma unroll
  for (int k2 = 0; k2 < 2; ++k2) {
    #pragma unroll
    for (int nfp = 0; nfp < 4; ++nfp) {
      float y[8];
      #pragma unroll
      for (int j = 0; j < 4; ++j) {
        y[j]     = fmaxf(accY[2 * k2][nfp][j]     + b2v[2 * k2][j],     0.f);
        y[j + 4] = fmaxf(accY[2 * k2 + 1][nfp][j] + b2v[2 * k2 + 1][j], 0.f);
      }
      S8 r;
      r.u[0] = pkbf(y[0], y[1]); r.u[1] = pkbf(y[2], y[3]);
      r.u[2] = pkbf(y[4], y[5]); r.u[3] = pkbf(y[6], y[7]);
      compD[nfp] = __builtin_amdgcn_mfma_f32_16x16x32_bf16(w3f[k2], r.s, compD[nfp], 0, 0, 0);
    }
  }

  // ---- comp -> LDS (b128, 2-way free) ----
  #pragma unroll
  for (int nfp = 0; nfp < 4; ++nfp) {
    f32x4 cv;
    #pragma unroll
    for (int jj = 0; jj < 4; ++jj) {
      int h = (g << 2) + jj;
      cv[jj] = (compD[nfp][jj] + b3_s[h]) * tp_s[h];
    }
    *(f32x4*)&comp_s[(wave << 6) + nfp * 16 + sl][g << 2] = cv;
  }
  __syncthreads();

  // ---- QK^T + bias; wave handles heads 4*wave..4*wave+3 ----
  const float scale = 0.125f;
  #pragma unroll
  for (int hh = 0; hh < 4; ++hh) {
    int h = (wave << 2) + hh;
    short8 aq[2], bk_[2];
    #pragma unroll
    for (int kk = 0; kk < 2; ++kk) {
      aq[kk]  = *(const short8*)(qp + (size_t)(b * NS + t0 + sl) * EE + (h << 6) + kk * 32 + (g << 3));
      bk_[kk] = *(const short8*)(kp + (size_t)(b * NS + s0 + sl) * EE + (h << 6) + kk * 32 + (g << 3));
    }
    f32x4 accS = zero;
    accS = __builtin_amdgcn_mfma_f32_16x16x32_bf16(aq[0], bk_[0], accS, 0, 0, 0);
    accS = __builtin_amdgcn_mfma_f32_16x16x32_bf16(aq[1], bk_[1], accS, 0, 0, 0);
    #pragma unroll
    for (int j = 0; j < 4; ++j) {
      int tl = (g << 2) + j;
      float v = accS[j] * scale + comp_s[tl * 16 + sl][h];
      scores[(size_t)((b * HH + h) * NS + t0 + tl) * NS + s0 + sl] = v;
    }
  }
}

// ---------------- fused softmax + PV (flash-style, scores read once) ----------------

__global__ __launch_bounds__(256, 2) void fused_softmax_pv(
    const float* __restrict__ scores,   // [B,H,512,512] f32
    const u16* __restrict__ vT,         // [B,H,64,512] bf16
    u16* __restrict__ attn_out) {       // [2048,1024] bf16
  const int tt = blockIdx.x, h = blockIdx.y, b = blockIdx.z;
  const int tid = threadIdx.x, lane = tid & 63, wave = tid >> 6;
  const int g = lane >> 4, sl = lane & 15;
  const int t0w = (tt << 6) + (wave << 4);
  const int trow = t0w + sl;

  // load this lane's A-fragment slice of its score row: 16 chunks x 8 f32
  const float* srow = scores + (((size_t)((b * HH + h) * NS + trow)) << 9) + (g << 3);
  f32x4 sc[32];
  #pragma unroll
  for (int ks = 0; ks < 16; ++ks) {
    sc[2 * ks]     = *(const f32x4*)(srow + ks * 32);
    sc[2 * ks + 1] = *(const f32x4*)(srow + ks * 32 + 4);
  }

  // row max (within-lane then across g-lanes)
  float m = -1e30f;
  #pragma unroll
  for (int i = 0; i < 32; ++i)
    m = fmaxf(m, fmaxf(fmaxf(sc[i][0], sc[i][1]), fmaxf(sc[i][2], sc[i][3])));
  m = fmaxf(m, __shfl_xor(m, 16, 64));
  m = fmaxf(m, __shfl_xor(m, 32, 64));

  // exp + sum + pack to bf16 A-fragments (unnormalized)
  float l = 0.f;
  short8 p[16];
  #pragma unroll
  for (int ks = 0; ks < 16; ++ks) {
    float e[8];
    #pragma unroll
    for (int j = 0; j < 4; ++j) {
      e[j]     = __expf(sc[2 * ks][j] - m);
      e[j + 4] = __expf(sc[2 * ks + 1][j] - m);
    }
    #pragma unroll
    for (int j = 0; j < 8; ++j) l += e[j];
    S8 r;
    r.u[0] = pkbf(e[0], e[1]); r.u[1] = pkbf(e[2], e[3]);
    r.u[2] = pkbf(e[4], e[5]); r.u[3] = pkbf(e[6], e[7]);
    p[ks] = r.s;
  }
  l += __shfl_xor(l, 16, 64);
  l += __shfl_xor(l, 32, 64);
  float linv_own = 1.0f / l;            // lane's own row (sl)

  // PV: O_unnorm = P @ V^T-rows
  const f32x4 zero = {0.f, 0.f, 0.f, 0.f};
  f32x4 acc[4];
  #pragma unroll
  for (int i = 0; i < 4; ++i) acc[i] = zero;
  const u16* vbase = vT + (((size_t)((b * HH + h) * DD)) << 9) + (g << 3);
  #pragma unroll
  for (int ks = 0; ks < 16; ++ks) {
    #pragma unroll
    for (int nf = 0; nf < 4; ++nf) {
      short8 vv = *(const short8*)(vbase + (((size_t)(nf * 16 + sl)) << 9) + ks * 32);
      acc[nf] = __builtin_amdgcn_mfma_f32_16x16x32_bf16(p[ks], vv, acc[nf], 0, 0, 0);
    }
  }

  // redistribute 1/l: C-layout row m = g*4+j, held at lane index m (g==0 lanes)
  float linv[4];
  #pragma unroll
  for (int j = 0; j < 4; ++j) linv[j] = __shfl(linv_own, (g << 2) + j, 64);

  #pragma unroll
  for (int nf = 0; nf < 4; ++nf)
    #pragma unroll
    for (int j = 0; j < 4; ++j) {
      int t = t0w + (g << 2) + j;
      int col = (h << 6) + nf * 16 + sl;
      attn_out[(size_t)(b * NS + t) * EE + col] = f2bfh(acc[nf][j] * linv[j]);
    }
}

// ---------------- launch ----------------

extern "C" void kernel_launch(void* const* d_in, const int* in_sizes, int n_in,
                              void* d_out, int out_size, void* d_ws, size_t ws_size,
                              hipStream_t stream) {
  const float* query = (const float*)d_in[0];
  const float* key   = (const float*)d_in[1];
  const float* value = (const float*)d_in[2];
  const float* se    = (const float*)d_in[3];
  const float* Wq = (const float*)d_in[4];  const float* bq = (const float*)d_in[5];
  const float* Wk = (const float*)d_in[6];  const float* bk = (const float*)d_in[7];
  const float* Wv = (const float*)d_in[8];  const float* bv = (const float*)d_in[9];
  const float* Wo = (const float*)d_in[10]; const float* bo = (const float*)d_in[11];
  const float* W1 = (const float*)d_in[12]; const float* b1 = (const float*)d_in[13];
  const float* W2 = (const float*)d_in[14]; const float* b2 = (const float*)d_in[15];
  const float* W3 = (const float*)d_in[16]; const float* b3 = (const float*)d_in[17];
  const float* temps = (const float*)d_in[18];

  char* p = (char*)d_ws;
  auto alloc = [&](size_t bytes) { char* r = p; p += (bytes + 255) & ~(size_t)255; return r; };
  u16* qb  = (u16*)alloc((size_t)MM * EE * 2);
  u16* kb  = (u16*)alloc((size_t)MM * EE * 2);
  u16* vb  = (u16*)alloc((size_t)MM * EE * 2);
  u16* WqT = (u16*)alloc((size_t)EE * EE * 2);
  u16* WkT = (u16*)alloc((size_t)EE * EE * 2);
  u16* WvT = (u16*)alloc((size_t)EE * EE * 2);
  u16* WoT = (u16*)alloc((size_t)EE * EE * 2);
  u16* W2T = (u16*)alloc(4096 * 2);
  u16* W3P = (u16*)alloc(1024 * 2);
  u16* qp  = (u16*)alloc((size_t)MM * EE * 2);
  u16* kp  = (u16*)alloc((size_t)MM * EE * 2);
  u16* vp  = (u16*)alloc((size_t)MM * EE * 2);
  u16* vTb = (u16*)alloc((size_t)MM * EE * 2);
  float* hi = (float*)alloc((size_t)MM * 64 * 4);
  float* hj = (float*)alloc((size_t)MM * 64 * 4);
  float* scores = (float*)alloc((size_t)BB * HH * NS * NS * 4);
  u16* attn_out = (u16*)alloc((size_t)MM * EE * 2);
  (void)ws_size; (void)in_sizes; (void)n_in; (void)out_size;

  cvt_inputs<<<3072, 256, 0, stream>>>(query, key, value, qb, kb, vb);
  cvt_w<<<dim3(32, 32, 4), 256, 0, stream>>>(Wq, Wk, Wv, Wo, WqT, WkT, WvT, WoT);
  cvt_w_small<<<1, 256, 0, stream>>>(W2, W3, W2T, W3P);
  hi_hj_kernel<<<512, 256, 0, stream>>>(se, W1, b1, hi, hj);
  gemm_proj<<<dim3(16, 8, 3), 256, 0, stream>>>(qb, kb, vb, WqT, WkT, WvT, bq, bk, bv, qp, kp, vp);
  transpose_v<<<1024, 256, 0, stream>>>(vp, vTb);
  bias_scores<<<dim3(32, 32, 4), 256, 0, stream>>>(hi, hj, W2T, W3P, b2, b3, temps, qp, kp, scores);
  fused_softmax_pv<<<dim3(8, 16, 4), 256, 0, stream>>>(scores, vTb, attn_out);
  gemm_final<<<dim3(16, 8, 1), 256, 0, stream>>>(attn_out, WoT, bo, (float*)d_out);
}

// Round 4
// 167.093 us; speedup vs baseline: 1.2916x; 1.0621x over previous
//
#include <hip/hip_runtime.h>
#include <hip/hip_bf16.h>

typedef unsigned short u16;
typedef short short8 __attribute__((ext_vector_type(8)));
typedef float f32x4 __attribute__((ext_vector_type(4)));
typedef unsigned short u16x4 __attribute__((ext_vector_type(4)));

#define BB 4
#define NS 512
#define EE 1024
#define HH 16
#define DD 64
#define MM (BB*NS)   // 2048

__device__ __forceinline__ u16 f2bfh(float x) {
  __hip_bfloat16 h = __float2bfloat16(x);
  union { __hip_bfloat16 h; u16 u; } c; c.h = h; return c.u;
}
__device__ __forceinline__ unsigned pkbf(float a, float b) {
  union { __hip_bfloat16 h; u16 u; } ca, cb;
  ca.h = __float2bfloat16(a); cb.h = __float2bfloat16(b);
  return (unsigned)ca.u | ((unsigned)cb.u << 16);
}
union S8 { short8 s; unsigned u[4]; };

__device__ __forceinline__ void gload_lds16(const void* g, void* l) {
  __builtin_amdgcn_global_load_lds(
      (const __attribute__((address_space(1))) unsigned int*)g,
      (__attribute__((address_space(3))) unsigned int*)l, 16, 0, 0);
}

// ---------------- converts ----------------

__global__ void cvt_inputs(const float* __restrict__ q, const float* __restrict__ k,
                           const float* __restrict__ v,
                           u16* __restrict__ qb, u16* __restrict__ kb, u16* __restrict__ vb) {
  size_t g = (size_t)blockIdx.x * 256 + threadIdx.x;
  size_t e = g << 3;
  int seg = (int)(e >> 21);
  size_t off = e & ((1u << 21) - 1);
  const float* src = seg == 0 ? q : (seg == 1 ? k : v);
  u16* dst = seg == 0 ? qb : (seg == 1 ? kb : vb);
  float4 f0 = *(const float4*)(src + off);
  float4 f1 = *(const float4*)(src + off + 4);
  S8 r;
  r.u[0] = pkbf(f0.x, f0.y); r.u[1] = pkbf(f0.z, f0.w);
  r.u[2] = pkbf(f1.x, f1.y); r.u[3] = pkbf(f1.z, f1.w);
  *(short8*)(dst + off) = r.s;
}

__global__ void cvt_w(const float* __restrict__ Wq, const float* __restrict__ Wk,
                      const float* __restrict__ Wv, const float* __restrict__ Wo,
                      u16* __restrict__ WqT, u16* __restrict__ WkT,
                      u16* __restrict__ WvT, u16* __restrict__ WoT) {
  int z = blockIdx.z;
  const float* W = z == 0 ? Wq : z == 1 ? Wk : z == 2 ? Wv : Wo;
  u16* WT = z == 0 ? WqT : z == 1 ? WkT : z == 2 ? WvT : WoT;
  int n0 = blockIdx.x << 5, k0 = blockIdx.y << 5;
  __shared__ float tile[32][33];
  int tx = threadIdx.x & 31, ty = threadIdx.x >> 5;
  #pragma unroll
  for (int i = 0; i < 4; ++i) {
    int r = (i << 3) + ty;
    tile[r][tx] = W[(size_t)(k0 + r) * EE + n0 + tx];
  }
  __syncthreads();
  #pragma unroll
  for (int i = 0; i < 4; ++i) {
    int r = (i << 3) + ty;
    WT[(size_t)(n0 + r) * EE + k0 + tx] = f2bfh(tile[tx][r]);
  }
}

__global__ void cvt_w_small(const float* __restrict__ W2, const float* __restrict__ W3,
                            u16* __restrict__ W2T, u16* __restrict__ W3P) {
  int tid = threadIdx.x;
  for (int i = tid; i < 4096; i += 256) {
    int n = i >> 6, k = i & 63;
    W2T[i] = f2bfh(W2[k * 64 + n]);
  }
  // W3P: layer-3 A-fragment slot (g,j) of call k2 holds W3[c][h], c = (2*k2+(j>=4))*16 + g*4 + (j&3)
  for (int i = tid; i < 1024; i += 256) {
    int h = i >> 6, rem = i & 63;
    int k2 = rem >> 5, gg = (rem >> 3) & 3, j = rem & 7;
    int c = (2 * k2 + (j >> 2)) * 16 + gg * 4 + (j & 3);
    W3P[i] = f2bfh(W3[c * 16 + h]);
  }
}

// ---------------- hi / hj ----------------

__global__ void hi_hj_kernel(const float* __restrict__ se, const float* __restrict__ W1,
                             const float* __restrict__ b1,
                             float* __restrict__ hi, float* __restrict__ hj) {
  int tid = threadIdx.x;
  int row = blockIdx.x * 4 + (tid >> 6);
  int c = tid & 63;
  float ah = b1[c], aj = 0.f;
  #pragma unroll 8
  for (int k = 0; k < 64; ++k) {
    float s = se[row * 64 + k];
    ah += s * W1[k * 64 + c];
    aj += s * W1[(k + 64) * 64 + c];
  }
  hi[row * 64 + c] = ah;
  hj[row * 64 + c] = aj;
}

// ---------------- main GEMM (M x 1024 @ 1024 x 1024, Bt = [N][K]) ----------------

template <bool F32OUT>
__device__ __forceinline__ void gemm_body(const u16* __restrict__ A, const u16* __restrict__ Bt,
                                          const float* __restrict__ bias, void* __restrict__ Cout) {
  __shared__ u16 As[128 * 32];
  __shared__ u16 Bs[128 * 32];
  const int tid = threadIdx.x, lane = tid & 63, wave = tid >> 6;
  const int m0 = blockIdx.x * 128, n0 = blockIdx.y * 128;
  const int wr = wave >> 1, wc = wave & 1;

  const f32x4 zero = {0.f, 0.f, 0.f, 0.f};
  f32x4 acc[4][4];
  #pragma unroll
  for (int i = 0; i < 4; ++i)
    #pragma unroll
    for (int j = 0; j < 4; ++j) acc[i][j] = zero;

  const int rA = lane >> 2;
  const int cA = (lane & 3) << 3;

  for (int kt = 0; kt < EE; kt += 32) {
    #pragma unroll
    for (int i = 0; i < 2; ++i) {
      int base = ((i << 2) + wave) << 9;
      int row = (base >> 5) + rA;
      gload_lds16(A  + (size_t)(m0 + row) * EE + kt + cA, As + base);
      gload_lds16(Bt + (size_t)(n0 + row) * EE + kt + cA, Bs + base);
    }
    __syncthreads();
    short8 af[4], bfr[4];
    #pragma unroll
    for (int mf = 0; mf < 4; ++mf) {
      int row = wr * 64 + mf * 16 + (lane & 15);
      af[mf] = *(const short8*)(As + row * 32 + ((lane >> 4) << 3));
    }
    #pragma unroll
    for (int nf = 0; nf < 4; ++nf) {
      int row = wc * 64 + nf * 16 + (lane & 15);
      bfr[nf] = *(const short8*)(Bs + row * 32 + ((lane >> 4) << 3));
    }
    #pragma unroll
    for (int mf = 0; mf < 4; ++mf)
      #pragma unroll
      for (int nf = 0; nf < 4; ++nf)
        acc[mf][nf] = __builtin_amdgcn_mfma_f32_16x16x32_bf16(af[mf], bfr[nf], acc[mf][nf], 0, 0, 0);
    __syncthreads();
  }

  #pragma unroll
  for (int mf = 0; mf < 4; ++mf) {
    #pragma unroll
    for (int nf = 0; nf < 4; ++nf) {
      int col = n0 + wc * 64 + nf * 16 + (lane & 15);
      float bv = bias[col];
      #pragma unroll
      for (int j = 0; j < 4; ++j) {
        int rowm = m0 + wr * 64 + mf * 16 + ((lane >> 4) << 2) + j;
        float v = acc[mf][nf][j] + bv;
        if (F32OUT) ((float*)Cout)[(size_t)rowm * EE + col] = v;
        else        ((u16*)Cout)[(size_t)rowm * EE + col] = f2bfh(v);
      }
    }
  }
}

__global__ __launch_bounds__(256, 2) void gemm_proj(
    const u16* __restrict__ qb, const u16* __restrict__ kb, const u16* __restrict__ vb,
    const u16* __restrict__ WqT, const u16* __restrict__ WkT, const u16* __restrict__ WvT,
    const float* __restrict__ bq, const float* __restrict__ bk, const float* __restrict__ bv_,
    u16* __restrict__ qp, u16* __restrict__ kp, u16* __restrict__ vp) {
  int z = blockIdx.z;
  const u16* A = z == 0 ? qb : (z == 1 ? kb : vb);
  const u16* Bt = z == 0 ? WqT : (z == 1 ? WkT : WvT);
  const float* bias = z == 0 ? bq : (z == 1 ? bk : bv_);
  u16* C = z == 0 ? qp : (z == 1 ? kp : vp);
  gemm_body<false>(A, Bt, bias, C);
}

__global__ __launch_bounds__(256, 2) void gemm_final(
    const u16* __restrict__ A, const u16* __restrict__ WoT,
    const float* __restrict__ bo, float* __restrict__ C) {
  gemm_body<true>(A, WoT, bo, C);
}

// ---------------- transpose V: [B,N,H,D] -> [B,H,D,N] ----------------

__global__ void transpose_v(const u16* __restrict__ vp, u16* __restrict__ vT) {
  int id = blockIdx.x;
  int b = id >> 8, rem = id & 255, h = rem >> 4, nt = rem & 15;
  int n0 = nt << 5;
  __shared__ u16 tile[32][72];
  int tid = threadIdx.x;
  int tx = tid & 63, ty = tid >> 6;
  #pragma unroll
  for (int i = 0; i < 8; ++i) {
    int r = (i << 2) + ty;
    tile[r][tx] = vp[(size_t)(b * NS + n0 + r) * EE + (h << 6) + tx];
  }
  __syncthreads();
  int nl = tid & 31, dsub = tid >> 5;
  #pragma unroll
  for (int i = 0; i < 8; ++i) {
    int d = (i << 3) + dsub;
    vT[(size_t)((b * HH + h) * DD + d) * NS + n0 + nl] = tile[nl][d];
  }
}

// ------- fused CAB MLP + QK^T + online softmax + PV (per s-quarter partials) -------

__global__ __launch_bounds__(256, 2) void fused_cab_attn(
    const float* __restrict__ hi, const float* __restrict__ hj,
    const u16* __restrict__ W2T, const u16* __restrict__ W3P,
    const float* __restrict__ b2, const float* __restrict__ b3,
    const float* __restrict__ temps,
    const u16* __restrict__ qp, const u16* __restrict__ kp,
    const u16* __restrict__ vT,
    float* __restrict__ Opart, float* __restrict__ mlpart) {
  const int tt = blockIdx.x, sq = blockIdx.y, b = blockIdx.z;
  const int t0 = tt << 4;
  const int tid = threadIdx.x, lane = tid & 63, wave = tid >> 6;
  const int g = lane >> 4, sl = lane & 15;

  __shared__ float hi_s[16][80];
  __shared__ float hj_s[32][65];
  __shared__ float b2_s[64];
  __shared__ float b3_s[16], tp_s[16];
  __shared__ float comp3[16 * 273];   // [h]*273 + [s]*17 + [t]
  __shared__ u16 Pl[16][16][40];      // [h][t][s-pad]

  // stage hi rows + consts
  {
    int r = tid >> 4, c4 = (tid & 15) << 2;
    float4 hv = *(const float4*)(hi + ((size_t)(b * NS + t0 + r) << 6) + c4);
    *(f32x4*)&hi_s[r][c4] = (f32x4){hv.x, hv.y, hv.z, hv.w};
    if (tid < 64) b2_s[tid] = b2[tid];
    else if (tid < 80) b3_s[tid - 64] = b3[tid - 64];
    else if (tid < 96) tp_s[tid - 80] = temps[tid - 80];
  }

  const f32x4 zero = {0.f, 0.f, 0.f, 0.f};
  f32x4 acc[4][4];          // [hh][nf] rows t=g*4+j, cols d=nf*16+sl
  #pragma unroll
  for (int i = 0; i < 4; ++i)
    #pragma unroll
    for (int j = 0; j < 4; ++j) acc[i][j] = zero;
  float m_run[4] = {-3e38f, -3e38f, -3e38f, -3e38f};
  float l_run[4] = {0.f, 0.f, 0.f, 0.f};

  for (int pr = 0; pr < 4; ++pr) {
    const int s0p = (sq << 7) + (pr << 5);
    __syncthreads();   // prior hj_s/comp3/Pl reads done
    // stage hj 32 rows (scalar stores, stride 65 -> ~2-way)
    {
      int r = tid >> 3, c8 = (tid & 7) << 3;
      const float* src = hj + ((size_t)(b * NS + s0p + r) << 6) + c8;
      float4 a = *(const float4*)(src);
      float4 bv = *(const float4*)(src + 4);
      hj_s[r][c8 + 0] = a.x;  hj_s[r][c8 + 1] = a.y;
      hj_s[r][c8 + 2] = a.z;  hj_s[r][c8 + 3] = a.w;
      hj_s[r][c8 + 4] = bv.x; hj_s[r][c8 + 5] = bv.y;
      hj_s[r][c8 + 6] = bv.z; hj_s[r][c8 + 7] = bv.w;
    }

    float vsc[2][4][4];   // [tau][hh][j]: S' for s = tau*16 + g*4 + j, t = sl

    #pragma unroll
    for (int ta = 0; ta < 2; ++ta) {
      __syncthreads();   // hj ready; comp3 safe to rewrite
      // ---- MLP for this 16-s tile -> comp3 ----
      {
        float hjv[2][8];
        #pragma unroll
        for (int kk = 0; kk < 2; ++kk)
          #pragma unroll
          for (int j = 0; j < 8; ++j)
            hjv[kk][j] = hj_s[(ta << 4) + sl][kk * 32 + (g << 3) + j];

        short8 w3f[2];
        #pragma unroll
        for (int k2 = 0; k2 < 2; ++k2)
          w3f[k2] = *(const short8*)(W3P + (sl << 6) + k2 * 32 + (g << 3));

        float b2v[4][4];
        #pragma unroll
        for (int mfc = 0; mfc < 4; ++mfc)
          #pragma unroll
          for (int jj = 0; jj < 4; ++jj)
            b2v[mfc][jj] = b2_s[mfc * 16 + (g << 2) + jj];

        #pragma unroll
        for (int nh = 0; nh < 2; ++nh) {
          short8 xb[2][2];
          #pragma unroll
          for (int q = 0; q < 2; ++q) {
            int tl = (wave << 2) + nh * 2 + q;
            #pragma unroll
            for (int kk = 0; kk < 2; ++kk) {
              int c0 = kk * 32 + (g << 3);
              f32x4 h0 = *(const f32x4*)&hi_s[tl][c0];
              f32x4 h1 = *(const f32x4*)&hi_s[tl][c0 + 4];
              float x[8];
              #pragma unroll
              for (int j = 0; j < 4; ++j) {
                x[j]     = fmaxf(h0[j] + hjv[kk][j], 0.f);
                x[j + 4] = fmaxf(h1[j] + hjv[kk][j + 4], 0.f);
              }
              S8 r;
              r.u[0] = pkbf(x[0], x[1]); r.u[1] = pkbf(x[2], x[3]);
              r.u[2] = pkbf(x[4], x[5]); r.u[3] = pkbf(x[6], x[7]);
              xb[q][kk] = r.s;
            }
          }
          f32x4 accY[4][2];
          #pragma unroll
          for (int i = 0; i < 4; ++i)
            #pragma unroll
            for (int q = 0; q < 2; ++q) accY[i][q] = zero;
          #pragma unroll
          for (int kk = 0; kk < 2; ++kk)
            #pragma unroll
            for (int mfc = 0; mfc < 4; ++mfc) {
              short8 w2 = *(const short8*)(W2T + ((mfc * 16 + sl) << 6) + kk * 32 + (g << 3));
              #pragma unroll
              for (int q = 0; q < 2; ++q)
                accY[mfc][q] = __builtin_amdgcn_mfma_f32_16x16x32_bf16(w2, xb[q][kk], accY[mfc][q], 0, 0, 0);
            }
          #pragma unroll
          for (int q = 0; q < 2; ++q) {
            f32x4 compD = zero;
            #pragma unroll
            for (int k2 = 0; k2 < 2; ++k2) {
              float y[8];
              #pragma unroll
              for (int j = 0; j < 4; ++j) {
                y[j]     = fmaxf(accY[2 * k2][q][j]     + b2v[2 * k2][j],     0.f);
                y[j + 4] = fmaxf(accY[2 * k2 + 1][q][j] + b2v[2 * k2 + 1][j], 0.f);
              }
              S8 r;
              r.u[0] = pkbf(y[0], y[1]); r.u[1] = pkbf(y[2], y[3]);
              r.u[2] = pkbf(y[4], y[5]); r.u[3] = pkbf(y[6], y[7]);
              compD = __builtin_amdgcn_mfma_f32_16x16x32_bf16(w3f[k2], r.s, compD, 0, 0, 0);
            }
            int tloc = (wave << 2) + nh * 2 + q;   // writer's t
            #pragma unroll
            for (int jj = 0; jj < 4; ++jj) {
              int h = (g << 2) + jj;
              comp3[h * 273 + sl * 17 + tloc] = (compD[jj] + b3_s[h]) * tp_s[h];
            }
          }
        }
      }
      __syncthreads();
      // ---- QK^T (swapped: mfma(K,Q)) -> lane holds t=sl, s=tau*16+g*4+j ----
      const int s0t = s0p + (ta << 4);
      #pragma unroll
      for (int hh = 0; hh < 4; ++hh) {
        int h = (wave << 2) + hh;
        const u16* qb_ = qp + (size_t)(b * NS + t0 + sl) * EE + (h << 6) + (g << 3);
        const u16* kb_ = kp + (size_t)(b * NS + s0t + sl) * EE + (h << 6) + (g << 3);
        f32x4 accS = zero;
        accS = __builtin_amdgcn_mfma_f32_16x16x32_bf16(*(const short8*)kb_, *(const short8*)qb_, accS, 0, 0, 0);
        accS = __builtin_amdgcn_mfma_f32_16x16x32_bf16(*(const short8*)(kb_ + 32), *(const short8*)(qb_ + 32), accS, 0, 0, 0);
        #pragma unroll
        for (int j = 0; j < 4; ++j)
          vsc[ta][hh][j] = accS[j] * 0.125f + comp3[h * 273 + ((g << 2) + j) * 17 + sl];
      }
    }

    // ---- online softmax over the 32-s pair + P -> Pl ----
    float cpv[4];
    #pragma unroll
    for (int hh = 0; hh < 4; ++hh) {
      float v0 = vsc[0][hh][0], v1 = vsc[0][hh][1], v2 = vsc[0][hh][2], v3 = vsc[0][hh][3];
      float v4 = vsc[1][hh][0], v5 = vsc[1][hh][1], v6 = vsc[1][hh][2], v7 = vsc[1][hh][3];
      float mx = fmaxf(fmaxf(fmaxf(v0, v1), fmaxf(v2, v3)), fmaxf(fmaxf(v4, v5), fmaxf(v6, v7)));
      mx = fmaxf(mx, __shfl_xor(mx, 16, 64));
      mx = fmaxf(mx, __shfl_xor(mx, 32, 64));
      float mnew = fmaxf(m_run[hh], mx);
      float c = __expf(m_run[hh] - mnew);
      m_run[hh] = mnew;
      float e0 = __expf(v0 - mnew), e1 = __expf(v1 - mnew), e2 = __expf(v2 - mnew), e3 = __expf(v3 - mnew);
      float e4 = __expf(v4 - mnew), e5 = __expf(v5 - mnew), e6 = __expf(v6 - mnew), e7 = __expf(v7 - mnew);
      float ps = ((e0 + e1) + (e2 + e3)) + ((e4 + e5) + (e6 + e7));
      ps += __shfl_xor(ps, 16, 64);
      ps += __shfl_xor(ps, 32, 64);
      l_run[hh] = l_run[hh] * c + ps;
      cpv[hh] = c;
      int h = (wave << 2) + hh;
      uint2 wA; wA.x = pkbf(e0, e1); wA.y = pkbf(e2, e3);
      uint2 wB; wB.x = pkbf(e4, e5); wB.y = pkbf(e6, e7);
      *(uint2*)&Pl[h][sl][(g << 2)]      = wA;   // s = 4g..4g+3
      *(uint2*)&Pl[h][sl][16 + (g << 2)] = wB;   // s = 16+4g..
    }
    __syncthreads();   // Pl visible

    // ---- PV accumulate (K=32) ----
    #pragma unroll
    for (int hh = 0; hh < 4; ++hh) {
      int h = (wave << 2) + hh;
      float cb[4];
      #pragma unroll
      for (int j = 0; j < 4; ++j) cb[j] = __shfl(cpv[hh], (g << 2) + j, 64);
      short8 pf = *(const short8*)&Pl[h][sl][(g << 3)];
      const u16* vb0 = vT + (size_t)((b * HH + h) * DD) * NS + s0p + (g << 3);
      #pragma unroll
      for (int nf = 0; nf < 4; ++nf) {
        #pragma unroll
        for (int j = 0; j < 4; ++j) acc[hh][nf][j] *= cb[j];
        short8 vv = *(const short8*)(vb0 + (size_t)(nf * 16 + sl) * NS);
        acc[hh][nf] = __builtin_amdgcn_mfma_f32_16x16x32_bf16(pf, vv, acc[hh][nf], 0, 0, 0);
      }
    }
  }

  // ---- store partials ----
  size_t obase = ((size_t)sq * MM + (size_t)b * NS + t0) * EE;
  #pragma unroll
  for (int hh = 0; hh < 4; ++hh) {
    int h = (wave << 2) + hh;
    #pragma unroll
    for (int nf = 0; nf < 4; ++nf)
      #pragma unroll
      for (int j = 0; j < 4; ++j)
        Opart[obase + (size_t)((g << 2) + j) * EE + (h << 6) + nf * 16 + sl] = acc[hh][nf][j];
  }
  if (g == 0) {
    #pragma unroll
    for (int hh = 0; hh < 4; ++hh) {
      int h = (wave << 2) + hh;
      size_t mlb = (((size_t)sq * MM + b * NS + t0 + sl) * HH + h) * 2;
      mlpart[mlb] = m_run[hh];
      mlpart[mlb + 1] = l_run[hh];
    }
  }
}

// ---------------- combine 4 s-quarter partials -> bf16 attn_out ----------------

__global__ void combine_pv(const float* __restrict__ Opart, const float* __restrict__ mlpart,
                           u16* __restrict__ attn_out) {
  int row = blockIdx.x;
  int tid = threadIdx.x;
  int c4 = tid << 2;
  int h = c4 >> 6;
  float m[4], l[4];
  #pragma unroll
  for (int pq = 0; pq < 4; ++pq) {
    size_t mb = (((size_t)pq * MM + row) * HH + h) * 2;
    m[pq] = mlpart[mb]; l[pq] = mlpart[mb + 1];
  }
  float M = fmaxf(fmaxf(m[0], m[1]), fmaxf(m[2], m[3]));
  float den = 0.f;
  f32x4 num = {0.f, 0.f, 0.f, 0.f};
  #pragma unroll
  for (int pq = 0; pq < 4; ++pq) {
    float w = __expf(m[pq] - M);
    den += w * l[pq];
    f32x4 o = *(const f32x4*)(Opart + ((size_t)pq * MM + row) * EE + c4);
    #pragma unroll
    for (int i = 0; i < 4; ++i) num[i] += w * o[i];
  }
  float r = 1.0f / den;
  u16x4 out;
  #pragma unroll
  for (int i = 0; i < 4; ++i) out[i] = f2bfh(num[i] * r);
  *(u16x4*)(attn_out + (size_t)row * EE + c4) = out;
}

// ---------------- launch ----------------

extern "C" void kernel_launch(void* const* d_in, const int* in_sizes, int n_in,
                              void* d_out, int out_size, void* d_ws, size_t ws_size,
                              hipStream_t stream) {
  const float* query = (const float*)d_in[0];
  const float* key   = (const float*)d_in[1];
  const float* value = (const float*)d_in[2];
  const float* se    = (const float*)d_in[3];
  const float* Wq = (const float*)d_in[4];  const float* bq = (const float*)d_in[5];
  const float* Wk = (const float*)d_in[6];  const float* bk = (const float*)d_in[7];
  const float* Wv = (const float*)d_in[8];  const float* bv = (const float*)d_in[9];
  const float* Wo = (const float*)d_in[10]; const float* bo = (const float*)d_in[11];
  const float* W1 = (const float*)d_in[12]; const float* b1 = (const float*)d_in[13];
  const float* W2 = (const float*)d_in[14]; const float* b2 = (const float*)d_in[15];
  const float* W3 = (const float*)d_in[16]; const float* b3 = (const float*)d_in[17];
  const float* temps = (const float*)d_in[18];

  char* p = (char*)d_ws;
  auto alloc = [&](size_t bytes) { char* r = p; p += (bytes + 255) & ~(size_t)255; return r; };
  u16* qb  = (u16*)alloc((size_t)MM * EE * 2);
  u16* kb  = (u16*)alloc((size_t)MM * EE * 2);
  u16* vb  = (u16*)alloc((size_t)MM * EE * 2);
  u16* WqT = (u16*)alloc((size_t)EE * EE * 2);
  u16* WkT = (u16*)alloc((size_t)EE * EE * 2);
  u16* WvT = (u16*)alloc((size_t)EE * EE * 2);
  u16* WoT = (u16*)alloc((size_t)EE * EE * 2);
  u16* W2T = (u16*)alloc(4096 * 2);
  u16* W3P = (u16*)alloc(1024 * 2);
  u16* qp  = (u16*)alloc((size_t)MM * EE * 2);
  u16* kp  = (u16*)alloc((size_t)MM * EE * 2);
  u16* vp  = (u16*)alloc((size_t)MM * EE * 2);
  u16* vTb = (u16*)alloc((size_t)MM * EE * 2);
  float* hi = (float*)alloc((size_t)MM * 64 * 4);
  float* hj = (float*)alloc((size_t)MM * 64 * 4);
  float* Opart = (float*)alloc((size_t)4 * MM * EE * 4);   // 32 MB
  float* mlpart = (float*)alloc((size_t)4 * MM * HH * 2 * 4);
  u16* attn_out = (u16*)alloc((size_t)MM * EE * 2);
  (void)ws_size; (void)in_sizes; (void)n_in; (void)out_size;

  cvt_inputs<<<3072, 256, 0, stream>>>(query, key, value, qb, kb, vb);
  cvt_w<<<dim3(32, 32, 4), 256, 0, stream>>>(Wq, Wk, Wv, Wo, WqT, WkT, WvT, WoT);
  cvt_w_small<<<1, 256, 0, stream>>>(W2, W3, W2T, W3P);
  hi_hj_kernel<<<512, 256, 0, stream>>>(se, W1, b1, hi, hj);
  gemm_proj<<<dim3(16, 8, 3), 256, 0, stream>>>(qb, kb, vb, WqT, WkT, WvT, bq, bk, bv, qp, kp, vp);
  transpose_v<<<1024, 256, 0, stream>>>(vp, vTb);
  fused_cab_attn<<<dim3(32, 4, 4), 256, 0, stream>>>(hi, hj, W2T, W3P, b2, b3, temps,
                                                     qp, kp, vTb, Opart, mlpart);
  combine_pv<<<MM, 256, 0, stream>>>(Opart, mlpart, attn_out);
  gemm_final<<<dim3(16, 8, 1), 256, 0, stream>>>(attn_out, WoT, bo, (float*)d_out);
}